// Round 13
// baseline (863.897 us; speedup 1.0000x reference)
//
#include <hip/hip_runtime.h>
#include <cmath>

#define NP  16000
#define NV  200
#define HH  256

typedef short short8 __attribute__((ext_vector_type(8)));
typedef float f32x4  __attribute__((ext_vector_type(4)));

__device__ __forceinline__ unsigned short f2b(float f) {
  union { float f; unsigned u; } x; x.f = f;
  unsigned r = x.u + 0x7fffu + ((x.u >> 16) & 1u);
  return (unsigned short)(r >> 16);
}
__device__ __forceinline__ float b2f(unsigned short h) {
  union { unsigned u; float f; } x; x.u = ((unsigned)h) << 16;
  return x.f;
}
__device__ __forceinline__ float b2f_lo(unsigned u) {
  union { unsigned v; float f; } x; x.v = u << 16; return x.f;
}
__device__ __forceinline__ float b2f_hi(unsigned u) {
  union { unsigned v; float f; } x; x.v = u & 0xffff0000u; return x.f;
}
__device__ __forceinline__ unsigned cvt2(float a, float b) {
  unsigned r;
  asm("v_cvt_pk_bf16_f32 %0, %1, %2" : "=v"(r) : "v"(a), "v"(b));
  return r;
}
__device__ __forceinline__ void gld16(const void* g, void* l) {
  __builtin_amdgcn_global_load_lds((const __attribute__((address_space(1))) void*)g,
                                   (__attribute__((address_space(3))) void*)l, 16, 0, 0);
}
__device__ __forceinline__ float sigm(float x) { return 1.f / (1.f + __expf(-x)); }
__device__ __forceinline__ float tanhfast(float x) {
  const float e = __expf(-2.f * fabsf(x));
  const float t = (1.f - e) / (1.f + e);
  return x < 0.f ? -t : t;
}
__device__ __forceinline__ int xcd_swz(int orig, int q, int r) {
  const int xcd = orig & 7, loc = orig >> 3;
  return (xcd < r ? xcd * (q + 1) : r * (q + 1) + (xcd - r) * q) + loc;
}

// ---------------------------------------------------------------------------
// Merged weight packs: blocks 0-255 Wtp | 256-511 Wta | 512-767 Wtv | 768-1535 W2t
__global__ __launch_bounds__(256) void pack_all(const float* __restrict__ Wp,
                                                const float* __restrict__ Wa,
                                                const float* __restrict__ Wv,
                                                const float* __restrict__ Wx,
                                                const float* __restrict__ Wh,
                                                unsigned short* __restrict__ Wtp,
                                                unsigned short* __restrict__ Wta,
                                                unsigned short* __restrict__ Wtv,
                                                unsigned short* __restrict__ W2t) {
  const int b = blockIdx.x, k = threadIdx.x;
  if (b < 768) {
    const float* W = b < 256 ? Wp : (b < 512 ? Wa : Wv);
    unsigned short* Wt = b < 256 ? Wtp : (b < 512 ? Wta : Wtv);
    const int n = b & 255;
    Wt[n * 256 + k] = f2b(W[k * 256 + n]);
  } else {
    const int col = b - 768;
    for (int kk = k; kk < 512; kk += 256)
      W2t[(size_t)col * 512 + kk] =
          f2b(kk < 256 ? Wx[(size_t)kk * 768 + col] : Wh[(size_t)(kk - 256) * 768 + col]);
  }
}

// ---------------------------------------------------------------------------
// Barrier-free embed GEMM: E = relu(X @ W + b). Tile 64x256, 512 thr / 8 waves
// (2 row-groups x 4 col-groups). A (fp32, consumed once) and B (bf16 Wt,
// L2-resident) load DIRECTLY global->register in MFMA fragment layout:
// lane l, tile (mi/nj), ks: elem = [base + 16*t_idx + (l&15)][c*64+ks*32+(l>>4)*8 .. +8].
// No LDS, no __syncthreads in the K-loop. LDS used only for the dense-store epilogue.
// ---------------------------------------------------------------------------
__global__ __launch_bounds__(512) void embed_all(
    const float* __restrict__ Xp, const float* __restrict__ Xa, const float* __restrict__ Xv,
    const unsigned short* __restrict__ Wtp, const unsigned short* __restrict__ Wta,
    const unsigned short* __restrict__ Wtv,
    const float* __restrict__ bp, const float* __restrict__ ba, const float* __restrict__ bvn,
    unsigned short* __restrict__ Ep, unsigned short* __restrict__ Ea,
    unsigned short* __restrict__ Ev) {
  __shared__ __align__(16) unsigned short lds[16896];  // epilogue: 64 rows x 264
  const int t = threadIdx.x, w = t >> 6, l = t & 63;
  const int bid = blockIdx.x;
  const float* Xf; const unsigned short* Wt; const float* bias; unsigned short* E;
  int m0;
  if (bid < 2000)      { Xf = Xp; Wt = Wtp; bias = bp;  E = Ep; m0 = bid * 64; }
  else if (bid < 4000) { Xf = Xa; Wt = Wta; bias = ba;  E = Ea; m0 = (bid - 2000) * 64; }
  else                 { Xf = Xv; Wt = Wtv; bias = bvn; E = Ev; m0 = (bid - 4000) * 64; }
  const int wrow = (w >> 2) * 32, wcol = (w & 3) * 64;
  const int lr = l & 15, lk = (l >> 4) * 8;

  f32x4 acc[2][4];
#pragma unroll
  for (int i = 0; i < 2; ++i)
#pragma unroll
    for (int j = 0; j < 4; ++j) acc[i][j] = {0.f, 0.f, 0.f, 0.f};

#pragma unroll
  for (int c = 0; c < 4; ++c) {
    const int k0 = c * 64;
    short8 bv[2][4];
#pragma unroll
    for (int ks = 0; ks < 2; ++ks)
#pragma unroll
      for (int nj = 0; nj < 4; ++nj) {
        const int col = wcol + nj * 16 + lr;
        bv[ks][nj] = *reinterpret_cast<const short8*>(Wt + (size_t)col * 256 + k0 + ks * 32 + lk);
      }
    short8 av[2][2];
#pragma unroll
    for (int ks = 0; ks < 2; ++ks)
#pragma unroll
      for (int mi = 0; mi < 2; ++mi) {
        const int row = wrow + mi * 16 + lr;
        const float* ap = Xf + (size_t)(m0 + row) * 256 + k0 + ks * 32 + lk;
        const float4 f0 = *reinterpret_cast<const float4*>(ap);
        const float4 f1 = *reinterpret_cast<const float4*>(ap + 4);
        union { unsigned u[4]; short8 s8; } cv;
        cv.u[0] = cvt2(f0.x, f0.y); cv.u[1] = cvt2(f0.z, f0.w);
        cv.u[2] = cvt2(f1.x, f1.y); cv.u[3] = cvt2(f1.z, f1.w);
        av[ks][mi] = cv.s8;
      }
#pragma unroll
    for (int ks = 0; ks < 2; ++ks)
#pragma unroll
      for (int mi = 0; mi < 2; ++mi)
#pragma unroll
        for (int nj = 0; nj < 4; ++nj)
          acc[mi][nj] = __builtin_amdgcn_mfma_f32_16x16x32_bf16(av[ks][mi], bv[ks][nj], acc[mi][nj], 0, 0, 0);
  }

  // Epilogue: stage 64x256 (bias+relu, stride 264) -> 64B/thread dense stores
#pragma unroll
  for (int nj = 0; nj < 4; ++nj) {
    const int col = wcol + nj * 16 + lr;
    const float bvv = bias[col];
#pragma unroll
    for (int mi = 0; mi < 2; ++mi)
#pragma unroll
      for (int e = 0; e < 4; ++e) {
        const int row = wrow + mi * 16 + (l >> 4) * 4 + e;
        lds[row * 264 + col] = f2b(fmaxf(acc[mi][nj][e] + bvv, 0.f));
      }
  }
  __syncthreads();
  {
    const int r2 = t >> 3, s2 = t & 7;
    const unsigned short* src = lds + r2 * 264 + s2 * 32;
    const uint4 v0 = *reinterpret_cast<const uint4*>(src);
    const uint4 v1 = *reinterpret_cast<const uint4*>(src + 8);
    const uint4 v2 = *reinterpret_cast<const uint4*>(src + 16);
    const uint4 v3 = *reinterpret_cast<const uint4*>(src + 24);
    uint4* dst = reinterpret_cast<uint4*>(E + (size_t)(m0 + r2) * 256 + s2 * 32);
    dst[0] = v0; dst[1] = v1; dst[2] = v2; dst[3] = v3;
  }
}

// ---------------------------------------------------------------------------
// Barrier-free GX GEMM: GX = vall @ Wx + b_gru (M=112000, N=768, K=256).
// Tile 64x256; A (bf16, consumed once) and B (W2t, L2-resident) direct
// global->register fragment loads. LDS only for epilogue.
// ---------------------------------------------------------------------------
__global__ __launch_bounds__(512) void gx_gemm(const unsigned short* __restrict__ Abf,
                                               const unsigned short* __restrict__ W2t,
                                               const float* __restrict__ bias,
                                               unsigned short* __restrict__ GX) {
  __shared__ __align__(16) unsigned short lds[16896];
  const int t = threadIdx.x, w = t >> 6, l = t & 63;
  const int work = xcd_swz(blockIdx.x, 656, 2);   // 5250 = 8*656+2
  const int m0 = (work / 3) * 64, n0 = (work % 3) * 256;
  const int wrow = (w >> 2) * 32, wcol = (w & 3) * 64;
  const int lr = l & 15, lk = (l >> 4) * 8;

  f32x4 acc[2][4];
#pragma unroll
  for (int i = 0; i < 2; ++i)
#pragma unroll
    for (int j = 0; j < 4; ++j) acc[i][j] = {0.f, 0.f, 0.f, 0.f};

#pragma unroll
  for (int c = 0; c < 4; ++c) {
    const int k0 = c * 64;
    short8 bv[2][4];
#pragma unroll
    for (int ks = 0; ks < 2; ++ks)
#pragma unroll
      for (int nj = 0; nj < 4; ++nj) {
        const int col = n0 + wcol + nj * 16 + lr;
        bv[ks][nj] = *reinterpret_cast<const short8*>(W2t + (size_t)col * 512 + k0 + ks * 32 + lk);
      }
    short8 av[2][2];
#pragma unroll
    for (int ks = 0; ks < 2; ++ks)
#pragma unroll
      for (int mi = 0; mi < 2; ++mi) {
        const int row = wrow + mi * 16 + lr;
        av[ks][mi] = *reinterpret_cast<const short8*>(Abf + (size_t)(m0 + row) * 256 + k0 + ks * 32 + lk);
      }
#pragma unroll
    for (int ks = 0; ks < 2; ++ks)
#pragma unroll
      for (int mi = 0; mi < 2; ++mi)
#pragma unroll
        for (int nj = 0; nj < 4; ++nj)
          acc[mi][nj] = __builtin_amdgcn_mfma_f32_16x16x32_bf16(av[ks][mi], bv[ks][nj], acc[mi][nj], 0, 0, 0);
  }

#pragma unroll
  for (int nj = 0; nj < 4; ++nj) {
    const int col = wcol + nj * 16 + lr;
    const float bvv = bias[n0 + col];
#pragma unroll
    for (int mi = 0; mi < 2; ++mi)
#pragma unroll
      for (int e = 0; e < 4; ++e) {
        const int row = wrow + mi * 16 + (l >> 4) * 4 + e;
        lds[row * 264 + col] = f2b(acc[mi][nj][e] + bvv);
      }
  }
  __syncthreads();
  {
    const int r2 = t >> 3, s2 = t & 7;
    const unsigned short* src = lds + r2 * 264 + s2 * 32;
    const uint4 v0 = *reinterpret_cast<const uint4*>(src);
    const uint4 v1 = *reinterpret_cast<const uint4*>(src + 8);
    const uint4 v2 = *reinterpret_cast<const uint4*>(src + 16);
    const uint4 v3 = *reinterpret_cast<const uint4*>(src + 24);
    uint4* dst = reinterpret_cast<uint4*>(GX + (size_t)(m0 + r2) * 768 + n0 + s2 * 32);
    dst[0] = v0; dst[1] = v1; dst[2] = v2; dst[3] = v3;
  }
}

// ---------------------------------------------------------------------------
// l_time from bf16 embeddings
// ---------------------------------------------------------------------------
__global__ __launch_bounds__(256) void ltime_kernel(const unsigned short* __restrict__ ep,
                                                    const unsigned short* __restrict__ ea,
                                                    const unsigned short* __restrict__ ev,
                                                    float* __restrict__ partials) {
  const unsigned PO = 3584000u, VO = 44800u;
  const unsigned TOT = 2u * PO + VO;
  const unsigned SL = 512000u, SLV = 6400u;
  const float wbig = 1.f / (3.f * 7.f * 16000.f);
  const float wsmall = 1.f / (3.f * 7.f * 200.f);
  float local = 0.f;
  for (unsigned i = blockIdx.x * 256u + threadIdx.x; i < TOT; i += gridDim.x * 256u) {
    const unsigned short* base; unsigned off, sl; float wgt;
    if (i < 2u * PO) { base = (i < PO) ? ep : ea; off = (i < PO) ? i : i - PO; sl = SL; wgt = wbig; }
    else             { base = ev; off = i - 2u * PO; sl = SLV; wgt = wsmall; }
    const uint4 u0 = *reinterpret_cast<const uint4*>(base + (size_t)off * 8);
    const uint4 u1 = *reinterpret_cast<const uint4*>(base + (size_t)(off + sl) * 8);
    float s = 0.f, d;
    d = b2f_lo(u1.x) - b2f_lo(u0.x); s += d * d;
    d = b2f_hi(u1.x) - b2f_hi(u0.x); s += d * d;
    d = b2f_lo(u1.y) - b2f_lo(u0.y); s += d * d;
    d = b2f_hi(u1.y) - b2f_hi(u0.y); s += d * d;
    d = b2f_lo(u1.z) - b2f_lo(u0.z); s += d * d;
    d = b2f_hi(u1.z) - b2f_hi(u0.z); s += d * d;
    d = b2f_lo(u1.w) - b2f_lo(u0.w); s += d * d;
    d = b2f_hi(u1.w) - b2f_hi(u0.w); s += d * d;
    local += wgt * s;
  }
  __shared__ float red[256];
  red[threadIdx.x] = local;
  __syncthreads();
  for (int s = 128; s > 0; s >>= 1) {
    if (threadIdx.x < s) red[threadIdx.x] += red[threadIdx.x + s];
    __syncthreads();
  }
  if (threadIdx.x == 0) partials[blockIdx.x] = red[0];
}

// ---------------------------------------------------------------------------
// v_all bf16: wave per n, lane handles 4 cols
// ---------------------------------------------------------------------------
__global__ __launch_bounds__(256) void vall_kernel(const unsigned short* __restrict__ ep,
                                                   const unsigned short* __restrict__ ea,
                                                   const unsigned short* __restrict__ ev,
                                                   const int* __restrict__ aidx,
                                                   const int* __restrict__ vidx,
                                                   const float* __restrict__ wm,
                                                   unsigned short* __restrict__ vall) {
  const int w = threadIdx.x >> 6, l = threadIdx.x & 63;
  const int n = blockIdx.x * 4 + w;
  float w0 = wm[0], w1 = wm[1], w2 = wm[2];
  const float mx = fmaxf(w0, fmaxf(w1, w2));
  const float e0 = expf(w0 - mx), e1 = expf(w1 - mx), e2 = expf(w2 - mx);
  const float inv = 1.f / (e0 + e1 + e2);
  w0 = e0 * inv; w1 = e1 * inv; w2 = e2 * inv;
  const int a0 = aidx[n * 4 + 0], a1 = aidx[n * 4 + 1];
  const int a2 = aidx[n * 4 + 2], a3 = aidx[n * 4 + 3];
  const int vn = vidx[n];
  const int cb = l * 4;
  for (int t = 0; t < 7; ++t) {
    const size_t tb = (size_t)t * NP * HH;
    const uint2 ua0 = *reinterpret_cast<const uint2*>(ea + tb + (size_t)a0 * HH + cb);
    const uint2 ua1 = *reinterpret_cast<const uint2*>(ea + tb + (size_t)a1 * HH + cb);
    const uint2 ua2 = *reinterpret_cast<const uint2*>(ea + tb + (size_t)a2 * HH + cb);
    const uint2 ua3 = *reinterpret_cast<const uint2*>(ea + tb + (size_t)a3 * HH + cb);
    const uint2 uv  = *reinterpret_cast<const uint2*>(ev + (size_t)t * NV * HH + (size_t)vn * HH + cb);
    const uint2 up  = *reinterpret_cast<const uint2*>(ep + tb + (size_t)n * HH + cb);
    float o[4];
    o[0] = w0 * 0.25f * (b2f_lo(ua0.x) + b2f_lo(ua1.x) + b2f_lo(ua2.x) + b2f_lo(ua3.x)) + w1 * b2f_lo(uv.x) + w2 * b2f_lo(up.x);
    o[1] = w0 * 0.25f * (b2f_hi(ua0.x) + b2f_hi(ua1.x) + b2f_hi(ua2.x) + b2f_hi(ua3.x)) + w1 * b2f_hi(uv.x) + w2 * b2f_hi(up.x);
    o[2] = w0 * 0.25f * (b2f_lo(ua0.y) + b2f_lo(ua1.y) + b2f_lo(ua2.y) + b2f_lo(ua3.y)) + w1 * b2f_lo(uv.y) + w2 * b2f_lo(up.y);
    o[3] = w0 * 0.25f * (b2f_hi(ua0.y) + b2f_hi(ua1.y) + b2f_hi(ua2.y) + b2f_hi(ua3.y)) + w1 * b2f_hi(uv.y) + w2 * b2f_hi(up.y);
    uint2 ov; ov.x = cvt2(o[0], o[1]); ov.y = cvt2(o[2], o[3]);
    *reinterpret_cast<uint2*>(vall + tb + (size_t)n * HH + cb) = ov;
  }
}

// ---------------------------------------------------------------------------
// GRU step 0 (h=0): H0 = (1 - sigmoid(gz)) * tanh(gn)
// ---------------------------------------------------------------------------
__global__ __launch_bounds__(256) void gru_h0(const unsigned short* __restrict__ GX,
                                              unsigned short* __restrict__ H0) {
  const int idx = blockIdx.x * 256 + threadIdx.x;
  const int hrow = idx >> 6, jq = idx & 63;
  const int g = (hrow >= 32000) ? 2 : (hrow >= 16000 ? 1 : 0);
  const int n = hrow - g * 16000;
  const size_t gxrow = (size_t)(4 + g) * 16000 + n;
  const unsigned short* gp = GX + gxrow * 768 + jq * 4;
  const uint2 uz = *reinterpret_cast<const uint2*>(gp + 256);
  const uint2 un = *reinterpret_cast<const uint2*>(gp + 512);
  float h[4];
  h[0] = (1.f - sigm(b2f_lo(uz.x))) * tanhfast(b2f_lo(un.x));
  h[1] = (1.f - sigm(b2f_hi(uz.x))) * tanhfast(b2f_hi(un.x));
  h[2] = (1.f - sigm(b2f_lo(uz.y))) * tanhfast(b2f_lo(un.y));
  h[3] = (1.f - sigm(b2f_hi(uz.y))) * tanhfast(b2f_hi(un.y));
  uint2 o; o.x = cvt2(h[0], h[1]); o.y = cvt2(h[2], h[3]);
  *reinterpret_cast<uint2*>(H0 + (size_t)hrow * 256 + jq * 4) = o;
}

// ---------------------------------------------------------------------------
// GRU recurrent step l (1..4): acc = Hsrc @ Wh (K=256, 3 gates);
// epilogue: gates from GX + acc -> Hdst via LDS (coalesced stores). (R9 version)
// ---------------------------------------------------------------------------
__global__ __launch_bounds__(512, 2) void gru_hstep(const unsigned short* __restrict__ GX,
                                                    const unsigned short* __restrict__ W2t,
                                                    const unsigned short* __restrict__ Hsrc,
                                                    unsigned short* __restrict__ Hdst,
                                                    int lstep) {
  __shared__ __align__(16) unsigned short lds[32768];  // As 8192 | Bs 24576
  unsigned short* As = lds;
  unsigned short* Bs = lds + 8192;
  const int t = threadIdx.x, w = t >> 6, l = t & 63;
  const int work = xcd_swz(blockIdx.x, 93, 6);  // 750 = 8*93+6
  const int bx = work >> 1, jb = work & 1;
  const int m0 = bx * 128, j0 = jb * 128;
  const int g = bx / 125;
  const size_t gxRowBase = (size_t)(4 + g - lstep) * 16000 + (size_t)(m0 - g * 16000);
  const int srow = l >> 3;
  const int scol = ((l & 7) ^ srow) * 8;
  const int wr = w >> 2, wj = w & 3;
  f32x4 acc[3][4][2];
#pragma unroll
  for (int gate = 0; gate < 3; ++gate)
#pragma unroll
    for (int mi = 0; mi < 4; ++mi)
#pragma unroll
      for (int nj = 0; nj < 2; ++nj) acc[gate][mi][nj] = {0.f, 0.f, 0.f, 0.f};

#pragma unroll
  for (int c = 0; c < 4; ++c) {
#pragma unroll
    for (int i = 0; i < 2; ++i) {
      const int seg = w * 2 + i;
      gld16(Hsrc + (size_t)(m0 + 8 * seg + srow) * 256 + c * 64 + scol, (void*)(As + seg * 512));
    }
#pragma unroll
    for (int i = 0; i < 6; ++i) {
      const int seg = w * 6 + i;
      const int tilerow = 8 * seg + srow;
      const int gate = tilerow >> 7, jj = tilerow & 127;
      gld16(W2t + (size_t)(gate * 256 + j0 + jj) * 512 + 256 + c * 64 + scol,
            (void*)(Bs + seg * 512));
    }
    __syncthreads();
#pragma unroll
    for (int ks = 0; ks < 2; ++ks) {
      short8 av[4];
#pragma unroll
      for (int mi = 0; mi < 4; ++mi) {
        const int r = wr * 64 + mi * 16 + (l & 15);
        const int slot = (ks * 4 + (l >> 4)) ^ (r & 7);
        av[mi] = *reinterpret_cast<const short8*>(As + r * 64 + slot * 8);
      }
#pragma unroll
      for (int gate = 0; gate < 3; ++gate) {
        short8 bv0, bv1;
        {
          const int r0 = gate * 128 + wj * 32 + (l & 15);
          const int s0 = (ks * 4 + (l >> 4)) ^ (r0 & 7);
          bv0 = *reinterpret_cast<const short8*>(Bs + r0 * 64 + s0 * 8);
          const int r1 = r0 + 16;
          const int s1 = (ks * 4 + (l >> 4)) ^ (r1 & 7);
          bv1 = *reinterpret_cast<const short8*>(Bs + r1 * 64 + s1 * 8);
        }
#pragma unroll
        for (int mi = 0; mi < 4; ++mi) {
          acc[gate][mi][0] = __builtin_amdgcn_mfma_f32_16x16x32_bf16(av[mi], bv0, acc[gate][mi][0], 0, 0, 0);
          acc[gate][mi][1] = __builtin_amdgcn_mfma_f32_16x16x32_bf16(av[mi], bv1, acc[gate][mi][1], 0, 0, 0);
        }
      }
    }
    __syncthreads();
  }
  // epilogue: gates -> LDS -> coalesced stores (wave tile 64 rows x 32 cols)
  unsigned short* ep = lds + w * 2560;  // 64 x 40 shorts
#pragma unroll
  for (int nj = 0; nj < 2; ++nj) {
    const int jcol = j0 + wj * 32 + nj * 16 + (l & 15);
#pragma unroll
    for (int mi = 0; mi < 4; ++mi) {
#pragma unroll
      for (int e = 0; e < 4; ++e) {
        const int rib = wr * 64 + mi * 16 + (l >> 4) * 4 + e;
        const size_t hidx = (size_t)(m0 + rib) * 256 + jcol;
        const size_t gxoff = (gxRowBase + rib) * 768 + jcol;
        const float aR = acc[0][mi][nj][e] + b2f(GX[gxoff]);
        const float aZ = acc[1][mi][nj][e] + b2f(GX[gxoff + 256]);
        const float hn = acc[2][mi][nj][e];
        const float xn = b2f(GX[gxoff + 512]);
        const float rg = sigm(aR);
        const float zg = sigm(aZ);
        const float ng = tanhfast(xn + rg * hn);
        const float ho = b2f(Hsrc[hidx]);
        const int rl = mi * 16 + (l >> 4) * 4 + e;
        ep[rl * 40 + nj * 16 + (l & 15)] = f2b((1.f - zg) * ng + zg * ho);
      }
    }
  }
  __syncthreads();
  {
    const int grow = m0 + wr * 64 + l;
#pragma unroll
    for (int j = 0; j < 4; ++j) {
      const uint4 v = *reinterpret_cast<const uint4*>(ep + l * 40 + j * 8);
      *reinterpret_cast<uint4*>(Hdst + (size_t)grow * 256 + j0 + wj * 32 + j * 8) = v;
    }
  }
}

// ---------------------------------------------------------------------------
// Survival head + per-row loss: thread per row
// ---------------------------------------------------------------------------
__device__ inline float softplusf(float x) { return x > 20.f ? x : log1pf(expf(x)); }

__global__ __launch_bounds__(256) void head_kernel(const unsigned short* __restrict__ Hbuf,
                                                   const float* __restrict__ We, const float* __restrict__ be,
                                                   const float* __restrict__ Wm, const float* __restrict__ bmu,
                                                   const float* __restrict__ Ws, const float* __restrict__ bsg,
                                                   const float* __restrict__ yt,
                                                   float* __restrict__ partials) {
  __shared__ float sWe[256], sWm[256], sWs[256];
  const int t = threadIdx.x;
  sWe[t] = We[t]; sWm[t] = Wm[t]; sWs[t] = Ws[t];
  __syncthreads();
  const int row = blockIdx.x * 256 + t;
  float loss = 0.f;
  if (row < 48000) {
    const unsigned short* h = Hbuf + (size_t)row * HH;
    float pe = 0.f, pm = 0.f, ps = 0.f;
#pragma unroll 4
    for (int k0 = 0; k0 < 256; k0 += 8) {
      const uint4 u = *reinterpret_cast<const uint4*>(h + k0);
      const float hv[8] = {b2f_lo(u.x), b2f_hi(u.x), b2f_lo(u.y), b2f_hi(u.y),
                           b2f_lo(u.z), b2f_hi(u.z), b2f_lo(u.w), b2f_hi(u.w)};
#pragma unroll
      for (int q = 0; q < 8; ++q) {
        const int k = k0 + q;
        pe += hv[q] * sWe[k]; pm += hv[q] * sWm[k]; ps += hv[q] * sWs[k];
      }
    }
    const float eta = softplusf(pe + be[0]);
    const float mu  = pm + bmu[0];
    const float sg  = softplusf(ps + bsg[0]) + 0.001f;
    const float inv = 1.f / (sg * 1.41421356237309515f);
    float prev = 0.f;
#pragma unroll
    for (int hz = 1; hz <= 5; ++hz) {
      const float z  = (logf((float)hz) - mu) * inv;
      const float yc = eta * 0.5f * (1.f + erff(z));
      const float yh = yc - prev; prev = yc;
      const float d  = log1pf(yt[(size_t)row * 5 + (hz - 1)] + 1.0f) - log1pf(yh);
      loss += d * d;
    }
  }
  __shared__ float red[256];
  red[t] = loss;
  __syncthreads();
  for (int s = 128; s > 0; s >>= 1) {
    if (t < s) red[t] += red[t + s];
    __syncthreads();
  }
  if (t == 0) partials[blockIdx.x] = red[0];
}

__global__ __launch_bounds__(256) void final_kernel(const float* __restrict__ lt,
                                                    const float* __restrict__ lp,
                                                    float* __restrict__ out) {
  __shared__ float r1[256], r2[256];
  float s1 = 0.f, s2 = 0.f;
  for (int i = threadIdx.x; i < 1024; i += 256) s1 += lt[i];
  for (int i = threadIdx.x; i < 188; i += 256) s2 += lp[i];
  r1[threadIdx.x] = s1; r2[threadIdx.x] = s2;
  __syncthreads();
  for (int s = 128; s > 0; s >>= 1) {
    if (threadIdx.x < s) { r1[threadIdx.x] += r1[threadIdx.x + s]; r2[threadIdx.x] += r2[threadIdx.x + s]; }
    __syncthreads();
  }
  if (threadIdx.x == 0) out[0] = r2[0] / 240000.f + 0.5f * r1[0];
}

// ---------------------------------------------------------------------------
extern "C" void kernel_launch(void* const* d_in, const int* in_sizes, int n_in,
                              void* d_out, int out_size, void* d_ws, size_t ws_size,
                              hipStream_t stream) {
  (void)in_sizes; (void)n_in; (void)out_size; (void)ws_size;
  const float* x_paper  = (const float*)d_in[0];
  const float* x_author = (const float*)d_in[1];
  const float* x_venue  = (const float*)d_in[2];
  const int*   aidx     = (const int*)d_in[3];
  const int*   vidx     = (const int*)d_in[4];
  const float* y_true   = (const float*)d_in[5];
  const float* W_paper  = (const float*)d_in[6];
  const float* b_paper  = (const float*)d_in[7];
  const float* W_author = (const float*)d_in[8];
  const float* b_author = (const float*)d_in[9];
  const float* W_venue  = (const float*)d_in[10];
  const float* b_venue  = (const float*)d_in[11];
  const float* w_meta   = (const float*)d_in[12];
  const float* Wx       = (const float*)d_in[13];
  const float* Wh       = (const float*)d_in[14];
  const float* b_gru    = (const float*)d_in[15];
  const float* W_eta    = (const float*)d_in[16];
  const float* b_eta    = (const float*)d_in[17];
  const float* W_mu     = (const float*)d_in[18];
  const float* b_mu     = (const float*)d_in[19];
  const float* W_sigma  = (const float*)d_in[20];
  const float* b_sigma  = (const float*)d_in[21];

  unsigned short* p = (unsigned short*)d_ws;
  unsigned short* va16 = p;  p += (size_t)7 * NP * 256;      // 28,672,000
  unsigned short* Hb0  = p;  p += (size_t)48000 * 256;       // 12,288,000
  unsigned short* Hb1  = p;  p += (size_t)48000 * 256;       // 12,288,000
  unsigned short* W2t  = p;  p += (size_t)768 * 512;         //    393,216
  unsigned short* GX   = p;  p += (size_t)112000 * 768;      // 86,016,000
  float* ltp = (float*)p;
  float* lpp = ltp + 1024;
  // overlays (inside GX region):
  unsigned short* ep16 = GX;
  unsigned short* ea16 = ep16 + (size_t)8 * NP * 256;
  unsigned short* ev16 = ea16 + (size_t)8 * NP * 256;
  unsigned short* Wtp  = ev16 + (size_t)8 * NV * 256;
  unsigned short* Wta  = Wtp + 65536;
  unsigned short* Wtv  = Wta + 65536;

  // merged packs
  pack_all<<<1536, 256, 0, stream>>>(W_paper, W_author, W_venue, Wx, Wh,
                                     Wtp, Wta, Wtv, W2t);

  // barrier-free merged embeddings (paper 2000 | author 2000 | venue 25), 64-row tiles
  embed_all<<<4025, 512, 0, stream>>>(x_paper, x_author, x_venue, Wtp, Wta, Wtv,
                                      b_paper, b_author, b_venue, ep16, ea16, ev16);

  ltime_kernel<<<1024, 256, 0, stream>>>(ep16, ea16, ev16, ltp);
  vall_kernel<<<NP / 4, 256, 0, stream>>>(ep16, ea16, ev16, aidx, vidx, w_meta, va16);

  // GX = vall @ Wx + b_gru (barrier-free)
  gx_gemm<<<5250, 512, 0, stream>>>(va16, W2t, b_gru, GX);

  // GRU: step0 elementwise, then 4 recurrent MFMA steps (ping-pong)
  gru_h0<<<12000, 256, 0, stream>>>(GX, Hb0);
  gru_hstep<<<750, 512, 0, stream>>>(GX, W2t, Hb0, Hb1, 1);
  gru_hstep<<<750, 512, 0, stream>>>(GX, W2t, Hb1, Hb0, 2);
  gru_hstep<<<750, 512, 0, stream>>>(GX, W2t, Hb0, Hb1, 3);
  gru_hstep<<<750, 512, 0, stream>>>(GX, W2t, Hb1, Hb0, 4);

  head_kernel<<<188, 256, 0, stream>>>(Hb0, W_eta, b_eta, W_mu, b_mu, W_sigma, b_sigma,
                                       y_true, lpp);
  final_kernel<<<1, 256, 0, stream>>>(ltp, lpp, (float*)d_out);
}

// Round 14
// 573.756 us; speedup vs baseline: 1.5057x; 1.5057x over previous
//
#include <hip/hip_runtime.h>
#include <cmath>

#define NP  16000
#define NV  200
#define HH  256

typedef short short8 __attribute__((ext_vector_type(8)));
typedef float f32x4  __attribute__((ext_vector_type(4)));

__device__ __forceinline__ unsigned short f2b(float f) {
  union { float f; unsigned u; } x; x.f = f;
  unsigned r = x.u + 0x7fffu + ((x.u >> 16) & 1u);
  return (unsigned short)(r >> 16);
}
__device__ __forceinline__ float b2f(unsigned short h) {
  union { unsigned u; float f; } x; x.u = ((unsigned)h) << 16;
  return x.f;
}
__device__ __forceinline__ float b2f_lo(unsigned u) {
  union { unsigned v; float f; } x; x.v = u << 16; return x.f;
}
__device__ __forceinline__ float b2f_hi(unsigned u) {
  union { unsigned v; float f; } x; x.v = u & 0xffff0000u; return x.f;
}
__device__ __forceinline__ unsigned cvt2(float a, float b) {
  unsigned r;
  asm("v_cvt_pk_bf16_f32 %0, %1, %2" : "=v"(r) : "v"(a), "v"(b));
  return r;
}
__device__ __forceinline__ void gld16(const void* g, void* l) {
  __builtin_amdgcn_global_load_lds((const __attribute__((address_space(1))) void*)g,
                                   (__attribute__((address_space(3))) void*)l, 16, 0, 0);
}
__device__ __forceinline__ float sigm(float x) { return 1.f / (1.f + __expf(-x)); }
__device__ __forceinline__ float tanhfast(float x) {
  const float e = __expf(-2.f * fabsf(x));
  const float t = (1.f - e) / (1.f + e);
  return x < 0.f ? -t : t;
}
__device__ __forceinline__ int xcd_swz(int orig, int q, int r) {
  const int xcd = orig & 7, loc = orig >> 3;
  return (xcd < r ? xcd * (q + 1) : r * (q + 1) + (xcd - r) * q) + loc;
}

// ---------------------------------------------------------------------------
// Merged weight packs: blocks 0-255 Wtp | 256-511 Wta | 512-767 Wtv | 768-1535 W2t
__global__ __launch_bounds__(256) void pack_all(const float* __restrict__ Wp,
                                                const float* __restrict__ Wa,
                                                const float* __restrict__ Wv,
                                                const float* __restrict__ Wx,
                                                const float* __restrict__ Wh,
                                                unsigned short* __restrict__ Wtp,
                                                unsigned short* __restrict__ Wta,
                                                unsigned short* __restrict__ Wtv,
                                                unsigned short* __restrict__ W2t) {
  const int b = blockIdx.x, k = threadIdx.x;
  if (b < 768) {
    const float* W = b < 256 ? Wp : (b < 512 ? Wa : Wv);
    unsigned short* Wt = b < 256 ? Wtp : (b < 512 ? Wta : Wtv);
    const int n = b & 255;
    Wt[n * 256 + k] = f2b(W[k * 256 + n]);
  } else {
    const int col = b - 768;
    for (int kk = k; kk < 512; kk += 256)
      W2t[(size_t)col * 512 + kk] =
          f2b(kk < 256 ? Wx[(size_t)kk * 768 + col] : Wh[(size_t)(kk - 256) * 768 + col]);
  }
}

// ---------------------------------------------------------------------------
// Embed GEMM, 2-phase double-buffered pipeline. Tile 64x256, 512 thr / 8 waves.
// stage(c+1) issued BEFORE frag-reads+MFMA of chunk c; one barrier per chunk.
// LDS: 2 x (As 4096 | Bs 16384) shorts = 80 KB; epilogue reuses base.
// ---------------------------------------------------------------------------
__global__ __launch_bounds__(512) void embed_all(
    const float* __restrict__ Xp, const float* __restrict__ Xa, const float* __restrict__ Xv,
    const unsigned short* __restrict__ Wtp, const unsigned short* __restrict__ Wta,
    const unsigned short* __restrict__ Wtv,
    const float* __restrict__ bp, const float* __restrict__ ba, const float* __restrict__ bvn,
    unsigned short* __restrict__ Ep, unsigned short* __restrict__ Ea,
    unsigned short* __restrict__ Ev) {
  __shared__ __align__(16) unsigned short lds[40960];  // [2][As 4096 | Bs 16384]
  const int t = threadIdx.x, w = t >> 6, l = t & 63;
  const int bid = blockIdx.x;
  const float* Xf; const unsigned short* Wt; const float* bias; unsigned short* E;
  int m0;
  if (bid < 2000)      { Xf = Xp; Wt = Wtp; bias = bp;  E = Ep; m0 = bid * 64; }
  else if (bid < 4000) { Xf = Xa; Wt = Wta; bias = ba;  E = Ea; m0 = (bid - 2000) * 64; }
  else                 { Xf = Xv; Wt = Wtv; bias = bvn; E = Ev; m0 = (bid - 4000) * 64; }
  const int srow = l >> 3, scol = ((l & 7) ^ srow) * 8;
  const int wrow = (w >> 2) * 32, wcol = (w & 3) * 64;
  const int arow = t >> 3, aseg = t & 7;
  const float* aptr = Xf + (size_t)(m0 + arow) * 256 + aseg * 8;
  const int aslot = aseg ^ (arow & 7);

  f32x4 acc[2][4];
#pragma unroll
  for (int i = 0; i < 2; ++i)
#pragma unroll
    for (int j = 0; j < 4; ++j) acc[i][j] = {0.f, 0.f, 0.f, 0.f};

  // prologue: chunk 0 into buf0
  {
    const float4 a0 = *reinterpret_cast<const float4*>(aptr);
    const float4 a1 = *reinterpret_cast<const float4*>(aptr + 4);
#pragma unroll
    for (int i = 0; i < 4; ++i) {
      const int seg = 4 * w + i;
      gld16(Wt + (size_t)(8 * seg + srow) * 256 + scol, (void*)(lds + 4096 + seg * 512));
    }
    uint4 u;
    u.x = cvt2(a0.x, a0.y); u.y = cvt2(a0.z, a0.w);
    u.z = cvt2(a1.x, a1.y); u.w = cvt2(a1.z, a1.w);
    *reinterpret_cast<uint4*>(lds + arow * 64 + aslot * 8) = u;
  }
  __syncthreads();

#pragma unroll
  for (int c = 0; c < 4; ++c) {
    unsigned short* As = lds + (c & 1) * 20480;
    unsigned short* Bs = As + 4096;
    unsigned short* Asn = lds + ((c + 1) & 1) * 20480;
    unsigned short* Bsn = Asn + 4096;
    float4 a0, a1;
    if (c < 3) {
      // issue next-chunk loads (stay in flight under the MFMAs)
      const float* np = aptr + (c + 1) * 64;
      a0 = *reinterpret_cast<const float4*>(np);
      a1 = *reinterpret_cast<const float4*>(np + 4);
#pragma unroll
      for (int i = 0; i < 4; ++i) {
        const int seg = 4 * w + i;
        gld16(Wt + (size_t)(8 * seg + srow) * 256 + (c + 1) * 64 + scol, (void*)(Bsn + seg * 512));
      }
    }
    // compute chunk c from buf[cur]
#pragma unroll
    for (int ks = 0; ks < 2; ++ks) {
      short8 av[2], bv[4];
#pragma unroll
      for (int mi = 0; mi < 2; ++mi) {
        const int r = wrow + mi * 16 + (l & 15);
        const int slot = (ks * 4 + (l >> 4)) ^ (r & 7);
        av[mi] = *reinterpret_cast<const short8*>(As + r * 64 + slot * 8);
      }
#pragma unroll
      for (int nj = 0; nj < 4; ++nj) {
        const int r = wcol + nj * 16 + (l & 15);
        const int slot = (ks * 4 + (l >> 4)) ^ (r & 7);
        bv[nj] = *reinterpret_cast<const short8*>(Bs + r * 64 + slot * 8);
      }
#pragma unroll
      for (int mi = 0; mi < 2; ++mi)
#pragma unroll
        for (int nj = 0; nj < 4; ++nj)
          acc[mi][nj] = __builtin_amdgcn_mfma_f32_16x16x32_bf16(av[ks == 0 ? mi : mi], bv[nj], acc[mi][nj], 0, 0, 0),
          (void)0;
    }
    if (c < 3) {
      // A arrived under the MFMAs; convert & write to next buffer
      uint4 u;
      u.x = cvt2(a0.x, a0.y); u.y = cvt2(a0.z, a0.w);
      u.z = cvt2(a1.x, a1.y); u.w = cvt2(a1.z, a1.w);
      *reinterpret_cast<uint4*>(Asn + arow * 64 + aslot * 8) = u;
    }
    __syncthreads();
  }

  // Epilogue: stage 64x256 (bias+relu, stride 264) at lds base -> dense stores
#pragma unroll
  for (int nj = 0; nj < 4; ++nj) {
    const int col = wcol + nj * 16 + (l & 15);
    const float bvv = bias[col];
#pragma unroll
    for (int mi = 0; mi < 2; ++mi)
#pragma unroll
      for (int e = 0; e < 4; ++e) {
        const int row = wrow + mi * 16 + (l >> 4) * 4 + e;
        lds[row * 264 + col] = f2b(fmaxf(acc[mi][nj][e] + bvv, 0.f));
      }
  }
  __syncthreads();
  {
    const int r2 = t >> 3, s2 = t & 7;
    const unsigned short* src = lds + r2 * 264 + s2 * 32;
    const uint4 v0 = *reinterpret_cast<const uint4*>(src);
    const uint4 v1 = *reinterpret_cast<const uint4*>(src + 8);
    const uint4 v2 = *reinterpret_cast<const uint4*>(src + 16);
    const uint4 v3 = *reinterpret_cast<const uint4*>(src + 24);
    uint4* dst = reinterpret_cast<uint4*>(E + (size_t)(m0 + r2) * 256 + s2 * 32);
    dst[0] = v0; dst[1] = v1; dst[2] = v2; dst[3] = v3;
  }
}

// ---------------------------------------------------------------------------
// GX GEMM, 2-phase double-buffered pipeline. Tile 64x256, 512 thr.
// ---------------------------------------------------------------------------
__global__ __launch_bounds__(512) void gx_gemm(const unsigned short* __restrict__ Abf,
                                               const unsigned short* __restrict__ W2t,
                                               const float* __restrict__ bias,
                                               unsigned short* __restrict__ GX) {
  __shared__ __align__(16) unsigned short lds[40960];  // [2][As 4096 | Bs 16384]
  const int t = threadIdx.x, w = t >> 6, l = t & 63;
  const int work = xcd_swz(blockIdx.x, 656, 2);   // 5250 = 8*656+2
  const int m0 = (work / 3) * 64, n0 = (work % 3) * 256;
  const int srow = l >> 3, scol = ((l & 7) ^ srow) * 8;
  const int wrow = (w >> 2) * 32, wcol = (w & 3) * 64;

  f32x4 acc[2][4];
#pragma unroll
  for (int i = 0; i < 2; ++i)
#pragma unroll
    for (int j = 0; j < 4; ++j) acc[i][j] = {0.f, 0.f, 0.f, 0.f};

  // prologue: chunk 0 into buf0
  gld16(Abf + (size_t)(m0 + 8 * w + srow) * 256 + scol, (void*)(lds + w * 512));
#pragma unroll
  for (int i = 0; i < 4; ++i) {
    const int seg = 4 * w + i;
    gld16(W2t + (size_t)(n0 + 8 * seg + srow) * 512 + scol, (void*)(lds + 4096 + seg * 512));
  }
  __syncthreads();

#pragma unroll
  for (int c = 0; c < 4; ++c) {
    unsigned short* As = lds + (c & 1) * 20480;
    unsigned short* Bs = As + 4096;
    unsigned short* Asn = lds + ((c + 1) & 1) * 20480;
    unsigned short* Bsn = Asn + 4096;
    if (c < 3) {
      gld16(Abf + (size_t)(m0 + 8 * w + srow) * 256 + (c + 1) * 64 + scol, (void*)(Asn + w * 512));
#pragma unroll
      for (int i = 0; i < 4; ++i) {
        const int seg = 4 * w + i;
        gld16(W2t + (size_t)(n0 + 8 * seg + srow) * 512 + (c + 1) * 64 + scol,
              (void*)(Bsn + seg * 512));
      }
    }
#pragma unroll
    for (int ks = 0; ks < 2; ++ks) {
      short8 av[2], bv[4];
#pragma unroll
      for (int mi = 0; mi < 2; ++mi) {
        const int r = wrow + mi * 16 + (l & 15);
        const int slot = (ks * 4 + (l >> 4)) ^ (r & 7);
        av[mi] = *reinterpret_cast<const short8*>(As + r * 64 + slot * 8);
      }
#pragma unroll
      for (int nj = 0; nj < 4; ++nj) {
        const int r = wcol + nj * 16 + (l & 15);
        const int slot = (ks * 4 + (l >> 4)) ^ (r & 7);
        bv[nj] = *reinterpret_cast<const short8*>(Bs + r * 64 + slot * 8);
      }
#pragma unroll
      for (int mi = 0; mi < 2; ++mi)
#pragma unroll
        for (int nj = 0; nj < 4; ++nj)
          acc[mi][nj] = __builtin_amdgcn_mfma_f32_16x16x32_bf16(av[mi], bv[nj], acc[mi][nj], 0, 0, 0);
    }
    __syncthreads();
  }

  // Epilogue
#pragma unroll
  for (int nj = 0; nj < 4; ++nj) {
    const int col = wcol + nj * 16 + (l & 15);
    const float bvv = bias[n0 + col];
#pragma unroll
    for (int mi = 0; mi < 2; ++mi)
#pragma unroll
      for (int e = 0; e < 4; ++e) {
        const int row = wrow + mi * 16 + (l >> 4) * 4 + e;
        lds[row * 264 + col] = f2b(acc[mi][nj][e] + bvv);
      }
  }
  __syncthreads();
  {
    const int r2 = t >> 3, s2 = t & 7;
    const unsigned short* src = lds + r2 * 264 + s2 * 32;
    const uint4 v0 = *reinterpret_cast<const uint4*>(src);
    const uint4 v1 = *reinterpret_cast<const uint4*>(src + 8);
    const uint4 v2 = *reinterpret_cast<const uint4*>(src + 16);
    const uint4 v3 = *reinterpret_cast<const uint4*>(src + 24);
    uint4* dst = reinterpret_cast<uint4*>(GX + (size_t)(m0 + r2) * 768 + n0 + s2 * 32);
    dst[0] = v0; dst[1] = v1; dst[2] = v2; dst[3] = v3;
  }
}

// ---------------------------------------------------------------------------
// l_time from bf16 embeddings
// ---------------------------------------------------------------------------
__global__ __launch_bounds__(256) void ltime_kernel(const unsigned short* __restrict__ ep,
                                                    const unsigned short* __restrict__ ea,
                                                    const unsigned short* __restrict__ ev,
                                                    float* __restrict__ partials) {
  const unsigned PO = 3584000u, VO = 44800u;
  const unsigned TOT = 2u * PO + VO;
  const unsigned SL = 512000u, SLV = 6400u;
  const float wbig = 1.f / (3.f * 7.f * 16000.f);
  const float wsmall = 1.f / (3.f * 7.f * 200.f);
  float local = 0.f;
  for (unsigned i = blockIdx.x * 256u + threadIdx.x; i < TOT; i += gridDim.x * 256u) {
    const unsigned short* base; unsigned off, sl; float wgt;
    if (i < 2u * PO) { base = (i < PO) ? ep : ea; off = (i < PO) ? i : i - PO; sl = SL; wgt = wbig; }
    else             { base = ev; off = i - 2u * PO; sl = SLV; wgt = wsmall; }
    const uint4 u0 = *reinterpret_cast<const uint4*>(base + (size_t)off * 8);
    const uint4 u1 = *reinterpret_cast<const uint4*>(base + (size_t)(off + sl) * 8);
    float s = 0.f, d;
    d = b2f_lo(u1.x) - b2f_lo(u0.x); s += d * d;
    d = b2f_hi(u1.x) - b2f_hi(u0.x); s += d * d;
    d = b2f_lo(u1.y) - b2f_lo(u0.y); s += d * d;
    d = b2f_hi(u1.y) - b2f_hi(u0.y); s += d * d;
    d = b2f_lo(u1.z) - b2f_lo(u0.z); s += d * d;
    d = b2f_hi(u1.z) - b2f_hi(u0.z); s += d * d;
    d = b2f_lo(u1.w) - b2f_lo(u0.w); s += d * d;
    d = b2f_hi(u1.w) - b2f_hi(u0.w); s += d * d;
    local += wgt * s;
  }
  __shared__ float red[256];
  red[threadIdx.x] = local;
  __syncthreads();
  for (int s = 128; s > 0; s >>= 1) {
    if (threadIdx.x < s) red[threadIdx.x] += red[threadIdx.x + s];
    __syncthreads();
  }
  if (threadIdx.x == 0) partials[blockIdx.x] = red[0];
}

// ---------------------------------------------------------------------------
// v_all bf16: wave per n, lane handles 4 cols
// ---------------------------------------------------------------------------
__global__ __launch_bounds__(256) void vall_kernel(const unsigned short* __restrict__ ep,
                                                   const unsigned short* __restrict__ ea,
                                                   const unsigned short* __restrict__ ev,
                                                   const int* __restrict__ aidx,
                                                   const int* __restrict__ vidx,
                                                   const float* __restrict__ wm,
                                                   unsigned short* __restrict__ vall) {
  const int w = threadIdx.x >> 6, l = threadIdx.x & 63;
  const int n = blockIdx.x * 4 + w;
  float w0 = wm[0], w1 = wm[1], w2 = wm[2];
  const float mx = fmaxf(w0, fmaxf(w1, w2));
  const float e0 = expf(w0 - mx), e1 = expf(w1 - mx), e2 = expf(w2 - mx);
  const float inv = 1.f / (e0 + e1 + e2);
  w0 = e0 * inv; w1 = e1 * inv; w2 = e2 * inv;
  const int a0 = aidx[n * 4 + 0], a1 = aidx[n * 4 + 1];
  const int a2 = aidx[n * 4 + 2], a3 = aidx[n * 4 + 3];
  const int vn = vidx[n];
  const int cb = l * 4;
  for (int t = 0; t < 7; ++t) {
    const size_t tb = (size_t)t * NP * HH;
    const uint2 ua0 = *reinterpret_cast<const uint2*>(ea + tb + (size_t)a0 * HH + cb);
    const uint2 ua1 = *reinterpret_cast<const uint2*>(ea + tb + (size_t)a1 * HH + cb);
    const uint2 ua2 = *reinterpret_cast<const uint2*>(ea + tb + (size_t)a2 * HH + cb);
    const uint2 ua3 = *reinterpret_cast<const uint2*>(ea + tb + (size_t)a3 * HH + cb);
    const uint2 uv  = *reinterpret_cast<const uint2*>(ev + (size_t)t * NV * HH + (size_t)vn * HH + cb);
    const uint2 up  = *reinterpret_cast<const uint2*>(ep + tb + (size_t)n * HH + cb);
    float o[4];
    o[0] = w0 * 0.25f * (b2f_lo(ua0.x) + b2f_lo(ua1.x) + b2f_lo(ua2.x) + b2f_lo(ua3.x)) + w1 * b2f_lo(uv.x) + w2 * b2f_lo(up.x);
    o[1] = w0 * 0.25f * (b2f_hi(ua0.x) + b2f_hi(ua1.x) + b2f_hi(ua2.x) + b2f_hi(ua3.x)) + w1 * b2f_hi(uv.x) + w2 * b2f_hi(up.x);
    o[2] = w0 * 0.25f * (b2f_lo(ua0.y) + b2f_lo(ua1.y) + b2f_lo(ua2.y) + b2f_lo(ua3.y)) + w1 * b2f_lo(uv.y) + w2 * b2f_lo(up.y);
    o[3] = w0 * 0.25f * (b2f_hi(ua0.y) + b2f_hi(ua1.y) + b2f_hi(ua2.y) + b2f_hi(ua3.y)) + w1 * b2f_hi(uv.y) + w2 * b2f_hi(up.y);
    uint2 ov; ov.x = cvt2(o[0], o[1]); ov.y = cvt2(o[2], o[3]);
    *reinterpret_cast<uint2*>(vall + tb + (size_t)n * HH + cb) = ov;
  }
}

// ---------------------------------------------------------------------------
// GRU step 0 (h=0): H0 = (1 - sigmoid(gz)) * tanh(gn)
// ---------------------------------------------------------------------------
__global__ __launch_bounds__(256) void gru_h0(const unsigned short* __restrict__ GX,
                                              unsigned short* __restrict__ H0) {
  const int idx = blockIdx.x * 256 + threadIdx.x;
  const int hrow = idx >> 6, jq = idx & 63;
  const int g = (hrow >= 32000) ? 2 : (hrow >= 16000 ? 1 : 0);
  const int n = hrow - g * 16000;
  const size_t gxrow = (size_t)(4 + g) * 16000 + n;
  const unsigned short* gp = GX + gxrow * 768 + jq * 4;
  const uint2 uz = *reinterpret_cast<const uint2*>(gp + 256);
  const uint2 un = *reinterpret_cast<const uint2*>(gp + 512);
  float h[4];
  h[0] = (1.f - sigm(b2f_lo(uz.x))) * tanhfast(b2f_lo(un.x));
  h[1] = (1.f - sigm(b2f_hi(uz.x))) * tanhfast(b2f_hi(un.x));
  h[2] = (1.f - sigm(b2f_lo(uz.y))) * tanhfast(b2f_lo(un.y));
  h[3] = (1.f - sigm(b2f_hi(uz.y))) * tanhfast(b2f_hi(un.y));
  uint2 o; o.x = cvt2(h[0], h[1]); o.y = cvt2(h[2], h[3]);
  *reinterpret_cast<uint2*>(H0 + (size_t)hrow * 256 + jq * 4) = o;
}

// ---------------------------------------------------------------------------
// GRU recurrent step l (1..4): acc = Hsrc @ Wh (K=256, 3 gates); (R9 version)
// ---------------------------------------------------------------------------
__global__ __launch_bounds__(512, 2) void gru_hstep(const unsigned short* __restrict__ GX,
                                                    const unsigned short* __restrict__ W2t,
                                                    const unsigned short* __restrict__ Hsrc,
                                                    unsigned short* __restrict__ Hdst,
                                                    int lstep) {
  __shared__ __align__(16) unsigned short lds[32768];  // As 8192 | Bs 24576
  unsigned short* As = lds;
  unsigned short* Bs = lds + 8192;
  const int t = threadIdx.x, w = t >> 6, l = t & 63;
  const int work = xcd_swz(blockIdx.x, 93, 6);  // 750 = 8*93+6
  const int bx = work >> 1, jb = work & 1;
  const int m0 = bx * 128, j0 = jb * 128;
  const int g = bx / 125;
  const size_t gxRowBase = (size_t)(4 + g - lstep) * 16000 + (size_t)(m0 - g * 16000);
  const int srow = l >> 3;
  const int scol = ((l & 7) ^ srow) * 8;
  const int wr = w >> 2, wj = w & 3;
  f32x4 acc[3][4][2];
#pragma unroll
  for (int gate = 0; gate < 3; ++gate)
#pragma unroll
    for (int mi = 0; mi < 4; ++mi)
#pragma unroll
      for (int nj = 0; nj < 2; ++nj) acc[gate][mi][nj] = {0.f, 0.f, 0.f, 0.f};

#pragma unroll
  for (int c = 0; c < 4; ++c) {
#pragma unroll
    for (int i = 0; i < 2; ++i) {
      const int seg = w * 2 + i;
      gld16(Hsrc + (size_t)(m0 + 8 * seg + srow) * 256 + c * 64 + scol, (void*)(As + seg * 512));
    }
#pragma unroll
    for (int i = 0; i < 6; ++i) {
      const int seg = w * 6 + i;
      const int tilerow = 8 * seg + srow;
      const int gate = tilerow >> 7, jj = tilerow & 127;
      gld16(W2t + (size_t)(gate * 256 + j0 + jj) * 512 + 256 + c * 64 + scol,
            (void*)(Bs + seg * 512));
    }
    __syncthreads();
#pragma unroll
    for (int ks = 0; ks < 2; ++ks) {
      short8 av[4];
#pragma unroll
      for (int mi = 0; mi < 4; ++mi) {
        const int r = wr * 64 + mi * 16 + (l & 15);
        const int slot = (ks * 4 + (l >> 4)) ^ (r & 7);
        av[mi] = *reinterpret_cast<const short8*>(As + r * 64 + slot * 8);
      }
#pragma unroll
      for (int gate = 0; gate < 3; ++gate) {
        short8 bv0, bv1;
        {
          const int r0 = gate * 128 + wj * 32 + (l & 15);
          const int s0 = (ks * 4 + (l >> 4)) ^ (r0 & 7);
          bv0 = *reinterpret_cast<const short8*>(Bs + r0 * 64 + s0 * 8);
          const int r1 = r0 + 16;
          const int s1 = (ks * 4 + (l >> 4)) ^ (r1 & 7);
          bv1 = *reinterpret_cast<const short8*>(Bs + r1 * 64 + s1 * 8);
        }
#pragma unroll
        for (int mi = 0; mi < 4; ++mi) {
          acc[gate][mi][0] = __builtin_amdgcn_mfma_f32_16x16x32_bf16(av[mi], bv0, acc[gate][mi][0], 0, 0, 0);
          acc[gate][mi][1] = __builtin_amdgcn_mfma_f32_16x16x32_bf16(av[mi], bv1, acc[gate][mi][1], 0, 0, 0);
        }
      }
    }
    __syncthreads();
  }
  // epilogue: gates -> LDS -> coalesced stores (wave tile 64 rows x 32 cols)
  unsigned short* ep = lds + w * 2560;  // 64 x 40 shorts
#pragma unroll
  for (int nj = 0; nj < 2; ++nj) {
    const int jcol = j0 + wj * 32 + nj * 16 + (l & 15);
#pragma unroll
    for (int mi = 0; mi < 4; ++mi) {
#pragma unroll
      for (int e = 0; e < 4; ++e) {
        const int rib = wr * 64 + mi * 16 + (l >> 4) * 4 + e;
        const size_t hidx = (size_t)(m0 + rib) * 256 + jcol;
        const size_t gxoff = (gxRowBase + rib) * 768 + jcol;
        const float aR = acc[0][mi][nj][e] + b2f(GX[gxoff]);
        const float aZ = acc[1][mi][nj][e] + b2f(GX[gxoff + 256]);
        const float hn = acc[2][mi][nj][e];
        const float xn = b2f(GX[gxoff + 512]);
        const float rg = sigm(aR);
        const float zg = sigm(aZ);
        const float ng = tanhfast(xn + rg * hn);
        const float ho = b2f(Hsrc[hidx]);
        const int rl = mi * 16 + (l >> 4) * 4 + e;
        ep[rl * 40 + nj * 16 + (l & 15)] = f2b((1.f - zg) * ng + zg * ho);
      }
    }
  }
  __syncthreads();
  {
    const int grow = m0 + wr * 64 + l;
#pragma unroll
    for (int j = 0; j < 4; ++j) {
      const uint4 v = *reinterpret_cast<const uint4*>(ep + l * 40 + j * 8);
      *reinterpret_cast<uint4*>(Hdst + (size_t)grow * 256 + j0 + wj * 32 + j * 8) = v;
    }
  }
}

// ---------------------------------------------------------------------------
// Survival head + per-row loss: thread per row
// ---------------------------------------------------------------------------
__device__ inline float softplusf(float x) { return x > 20.f ? x : log1pf(expf(x)); }

__global__ __launch_bounds__(256) void head_kernel(const unsigned short* __restrict__ Hbuf,
                                                   const float* __restrict__ We, const float* __restrict__ be,
                                                   const float* __restrict__ Wm, const float* __restrict__ bmu,
                                                   const float* __restrict__ Ws, const float* __restrict__ bsg,
                                                   const float* __restrict__ yt,
                                                   float* __restrict__ partials) {
  __shared__ float sWe[256], sWm[256], sWs[256];
  const int t = threadIdx.x;
  sWe[t] = We[t]; sWm[t] = Wm[t]; sWs[t] = Ws[t];
  __syncthreads();
  const int row = blockIdx.x * 256 + t;
  float loss = 0.f;
  if (row < 48000) {
    const unsigned short* h = Hbuf + (size_t)row * HH;
    float pe = 0.f, pm = 0.f, ps = 0.f;
#pragma unroll 4
    for (int k0 = 0; k0 < 256; k0 += 8) {
      const uint4 u = *reinterpret_cast<const uint4*>(h + k0);
      const float hv[8] = {b2f_lo(u.x), b2f_hi(u.x), b2f_lo(u.y), b2f_hi(u.y),
                           b2f_lo(u.z), b2f_hi(u.z), b2f_lo(u.w), b2f_hi(u.w)};
#pragma unroll
      for (int q = 0; q < 8; ++q) {
        const int k = k0 + q;
        pe += hv[q] * sWe[k]; pm += hv[q] * sWm[k]; ps += hv[q] * sWs[k];
      }
    }
    const float eta = softplusf(pe + be[0]);
    const float mu  = pm + bmu[0];
    const float sg  = softplusf(ps + bsg[0]) + 0.001f;
    const float inv = 1.f / (sg * 1.41421356237309515f);
    float prev = 0.f;
#pragma unroll
    for (int hz = 1; hz <= 5; ++hz) {
      const float z  = (logf((float)hz) - mu) * inv;
      const float yc = eta * 0.5f * (1.f + erff(z));
      const float yh = yc - prev; prev = yc;
      const float d  = log1pf(yt[(size_t)row * 5 + (hz - 1)] + 1.0f) - log1pf(yh);
      loss += d * d;
    }
  }
  __shared__ float red[256];
  red[t] = loss;
  __syncthreads();
  for (int s = 128; s > 0; s >>= 1) {
    if (t < s) red[t] += red[t + s];
    __syncthreads();
  }
  if (t == 0) partials[blockIdx.x] = red[0];
}

__global__ __launch_bounds__(256) void final_kernel(const float* __restrict__ lt,
                                                    const float* __restrict__ lp,
                                                    float* __restrict__ out) {
  __shared__ float r1[256], r2[256];
  float s1 = 0.f, s2 = 0.f;
  for (int i = threadIdx.x; i < 1024; i += 256) s1 += lt[i];
  for (int i = threadIdx.x; i < 188; i += 256) s2 += lp[i];
  r1[threadIdx.x] = s1; r2[threadIdx.x] = s2;
  __syncthreads();
  for (int s = 128; s > 0; s >>= 1) {
    if (threadIdx.x < s) { r1[threadIdx.x] += r1[threadIdx.x + s]; r2[threadIdx.x] += r2[threadIdx.x + s]; }
    __syncthreads();
  }
  if (threadIdx.x == 0) out[0] = r2[0] / 240000.f + 0.5f * r1[0];
}

// ---------------------------------------------------------------------------
extern "C" void kernel_launch(void* const* d_in, const int* in_sizes, int n_in,
                              void* d_out, int out_size, void* d_ws, size_t ws_size,
                              hipStream_t stream) {
  (void)in_sizes; (void)n_in; (void)out_size; (void)ws_size;
  const float* x_paper  = (const float*)d_in[0];
  const float* x_author = (const float*)d_in[1];
  const float* x_venue  = (const float*)d_in[2];
  const int*   aidx     = (const int*)d_in[3];
  const int*   vidx     = (const int*)d_in[4];
  const float* y_true   = (const float*)d_in[5];
  const float* W_paper  = (const float*)d_in[6];
  const float* b_paper  = (const float*)d_in[7];
  const float* W_author = (const float*)d_in[8];
  const float* b_author = (const float*)d_in[9];
  const float* W_venue  = (const float*)d_in[10];
  const float* b_venue  = (const float*)d_in[11];
  const float* w_meta   = (const float*)d_in[12];
  const float* Wx       = (const float*)d_in[13];
  const float* Wh       = (const float*)d_in[14];
  const float* b_gru    = (const float*)d_in[15];
  const float* W_eta    = (const float*)d_in[16];
  const float* b_eta    = (const float*)d_in[17];
  const float* W_mu     = (const float*)d_in[18];
  const float* b_mu     = (const float*)d_in[19];
  const float* W_sigma  = (const float*)d_in[20];
  const float* b_sigma  = (const float*)d_in[21];

  unsigned short* p = (unsigned short*)d_ws;
  unsigned short* va16 = p;  p += (size_t)7 * NP * 256;      // 28,672,000
  unsigned short* Hb0  = p;  p += (size_t)48000 * 256;       // 12,288,000
  unsigned short* Hb1  = p;  p += (size_t)48000 * 256;       // 12,288,000
  unsigned short* W2t  = p;  p += (size_t)768 * 512;         //    393,216
  unsigned short* GX   = p;  p += (size_t)112000 * 768;      // 86,016,000
  float* ltp = (float*)p;
  float* lpp = ltp + 1024;
  // overlays (inside GX region):
  unsigned short* ep16 = GX;
  unsigned short* ea16 = ep16 + (size_t)8 * NP * 256;
  unsigned short* ev16 = ea16 + (size_t)8 * NP * 256;
  unsigned short* Wtp  = ev16 + (size_t)8 * NV * 256;
  unsigned short* Wta  = Wtp + 65536;
  unsigned short* Wtv  = Wta + 65536;

  // merged packs
  pack_all<<<1536, 256, 0, stream>>>(W_paper, W_author, W_venue, Wx, Wh,
                                     Wtp, Wta, Wtv, W2t);

  // merged embeddings (paper 2000 | author 2000 | venue 25), 64-row tiles, dbuf pipeline
  embed_all<<<4025, 512, 0, stream>>>(x_paper, x_author, x_venue, Wtp, Wta, Wtv,
                                      b_paper, b_author, b_venue, ep16, ea16, ev16);

  ltime_kernel<<<1024, 256, 0, stream>>>(ep16, ea16, ev16, ltp);
  vall_kernel<<<NP / 4, 256, 0, stream>>>(ep16, ea16, ev16, aidx, vidx, w_meta, va16);

  // GX = vall @ Wx + b_gru (dbuf pipeline)
  gx_gemm<<<5250, 512, 0, stream>>>(va16, W2t, b_gru, GX);

  // GRU: step0 elementwise, then 4 recurrent MFMA steps (ping-pong)
  gru_h0<<<12000, 256, 0, stream>>>(GX, Hb0);
  gru_hstep<<<750, 512, 0, stream>>>(GX, W2t, Hb0, Hb1, 1);
  gru_hstep<<<750, 512, 0, stream>>>(GX, W2t, Hb1, Hb0, 2);
  gru_hstep<<<750, 512, 0, stream>>>(GX, W2t, Hb0, Hb1, 3);
  gru_hstep<<<750, 512, 0, stream>>>(GX, W2t, Hb1, Hb0, 4);

  head_kernel<<<188, 256, 0, stream>>>(Hb0, W_eta, b_eta, W_mu, b_mu, W_sigma, b_sigma,
                                       y_true, lpp);
  final_kernel<<<1, 256, 0, stream>>>(ltp, lpp, (float*)d_out);
}

// Round 15
// 560.943 us; speedup vs baseline: 1.5401x; 1.0228x over previous
//
#include <hip/hip_runtime.h>
#include <cmath>

#define NP  16000
#define NV  200
#define HH  256

typedef short short8 __attribute__((ext_vector_type(8)));
typedef float f32x4  __attribute__((ext_vector_type(4)));

__device__ __forceinline__ unsigned short f2b(float f) {
  union { float f; unsigned u; } x; x.f = f;
  unsigned r = x.u + 0x7fffu + ((x.u >> 16) & 1u);
  return (unsigned short)(r >> 16);
}
__device__ __forceinline__ float b2f(unsigned short h) {
  union { unsigned u; float f; } x; x.u = ((unsigned)h) << 16;
  return x.f;
}
__device__ __forceinline__ float b2f_lo(unsigned u) {
  union { unsigned v; float f; } x; x.v = u << 16; return x.f;
}
__device__ __forceinline__ float b2f_hi(unsigned u) {
  union { unsigned v; float f; } x; x.v = u & 0xffff0000u; return x.f;
}
__device__ __forceinline__ unsigned cvt2(float a, float b) {
  unsigned r;
  asm("v_cvt_pk_bf16_f32 %0, %1, %2" : "=v"(r) : "v"(a), "v"(b));
  return r;
}
__device__ __forceinline__ void gld16(const void* g, void* l) {
  __builtin_amdgcn_global_load_lds((const __attribute__((address_space(1))) void*)g,
                                   (__attribute__((address_space(3))) void*)l, 16, 0, 0);
}
__device__ __forceinline__ float sigm(float x) { return 1.f / (1.f + __expf(-x)); }
__device__ __forceinline__ float tanhfast(float x) {
  const float e = __expf(-2.f * fabsf(x));
  const float t = (1.f - e) / (1.f + e);
  return x < 0.f ? -t : t;
}
__device__ __forceinline__ int xcd_swz(int orig, int q, int r) {
  const int xcd = orig & 7, loc = orig >> 3;
  return (xcd < r ? xcd * (q + 1) : r * (q + 1) + (xcd - r) * q) + loc;
}

// ---------------------------------------------------------------------------
// Merged weight packs: blocks 0-255 Wtp | 256-511 Wta | 512-767 Wtv | 768-1535 W2t
__global__ __launch_bounds__(256) void pack_all(const float* __restrict__ Wp,
                                                const float* __restrict__ Wa,
                                                const float* __restrict__ Wv,
                                                const float* __restrict__ Wx,
                                                const float* __restrict__ Wh,
                                                unsigned short* __restrict__ Wtp,
                                                unsigned short* __restrict__ Wta,
                                                unsigned short* __restrict__ Wtv,
                                                unsigned short* __restrict__ W2t) {
  const int b = blockIdx.x, k = threadIdx.x;
  if (b < 768) {
    const float* W = b < 256 ? Wp : (b < 512 ? Wa : Wv);
    unsigned short* Wt = b < 256 ? Wtp : (b < 512 ? Wta : Wtv);
    const int n = b & 255;
    Wt[n * 256 + k] = f2b(W[k * 256 + n]);
  } else {
    const int col = b - 768;
    for (int kk = k; kk < 512; kk += 256)
      W2t[(size_t)col * 512 + kk] =
          f2b(kk < 256 ? Wx[(size_t)kk * 768 + col] : Wh[(size_t)(kk - 256) * 768 + col]);
  }
}

// ---------------------------------------------------------------------------
// Embed GEMM, BK=128: tile 64x256, 512 thr / 8 waves, K=256 in 2 chunks of 128.
// Only 4 barrier drains per block (was 8); per-phase load batch doubled.
// LDS: As [64][128] + Bs [256][128], 16-slot XOR swizzle; 80 KB (2 blocks/CU).
// ---------------------------------------------------------------------------
__global__ __launch_bounds__(512) void embed_all(
    const float* __restrict__ Xp, const float* __restrict__ Xa, const float* __restrict__ Xv,
    const unsigned short* __restrict__ Wtp, const unsigned short* __restrict__ Wta,
    const unsigned short* __restrict__ Wtv,
    const float* __restrict__ bp, const float* __restrict__ ba, const float* __restrict__ bvn,
    unsigned short* __restrict__ Ep, unsigned short* __restrict__ Ea,
    unsigned short* __restrict__ Ev) {
  __shared__ __align__(16) unsigned short lds[40960];  // As 8192 | Bs 32768 shorts
  unsigned short* As = lds;
  unsigned short* Bs = lds + 8192;
  const int t = threadIdx.x, w = t >> 6, l = t & 63;
  const int bid = blockIdx.x;
  const float* Xf; const unsigned short* Wt; const float* bias; unsigned short* E;
  int m0;
  if (bid < 2000)      { Xf = Xp; Wt = Wtp; bias = bp;  E = Ep; m0 = bid * 64; }
  else if (bid < 4000) { Xf = Xa; Wt = Wta; bias = ba;  E = Ea; m0 = (bid - 2000) * 64; }
  else                 { Xf = Xv; Wt = Wtv; bias = bvn; E = Ev; m0 = (bid - 4000) * 64; }
  const int wrow = (w >> 2) * 32, wcol = (w & 3) * 64;
  const int arow = t >> 3, aseg = t & 7;
  const float* aptr = Xf + (size_t)(m0 + arow) * 256 + aseg * 16;
  const int as0 = (aseg * 2) ^ (arow & 7), as1 = (aseg * 2 + 1) ^ (arow & 7);

  f32x4 acc[2][4];
#pragma unroll
  for (int i = 0; i < 2; ++i)
#pragma unroll
    for (int j = 0; j < 4; ++j) acc[i][j] = {0.f, 0.f, 0.f, 0.f};

#pragma unroll
  for (int c = 0; c < 2; ++c) {
    // B: 256 rows x 128 k via 8 gld16/thread; pre-swizzled global source
#pragma unroll
    for (int i = 0; i < 8; ++i) {
      const int r4 = w * 8 + i;                 // 0..63, each covers 4 rows
      const int row = r4 * 4 + (l >> 4);
      const int slot = (l & 15) ^ (row & 7);
      gld16(Wt + (size_t)row * 256 + c * 128 + slot * 8, (void*)(Bs + r4 * 512));
    }
    // A: 16 fp32/thread -> cvt -> 2 swizzled uint4 LDS writes
    {
      const float* ap = aptr + c * 128;
      const float4 f0 = *reinterpret_cast<const float4*>(ap);
      const float4 f1 = *reinterpret_cast<const float4*>(ap + 4);
      const float4 f2 = *reinterpret_cast<const float4*>(ap + 8);
      const float4 f3 = *reinterpret_cast<const float4*>(ap + 12);
      uint4 u0, u1;
      u0.x = cvt2(f0.x, f0.y); u0.y = cvt2(f0.z, f0.w);
      u0.z = cvt2(f1.x, f1.y); u0.w = cvt2(f1.z, f1.w);
      u1.x = cvt2(f2.x, f2.y); u1.y = cvt2(f2.z, f2.w);
      u1.z = cvt2(f3.x, f3.y); u1.w = cvt2(f3.z, f3.w);
      *reinterpret_cast<uint4*>(As + arow * 128 + as0 * 8) = u0;
      *reinterpret_cast<uint4*>(As + arow * 128 + as1 * 8) = u1;
    }
    __syncthreads();
#pragma unroll
    for (int ks = 0; ks < 4; ++ks) {
      short8 av[2], bv[4];
#pragma unroll
      for (int mi = 0; mi < 2; ++mi) {
        const int r = wrow + mi * 16 + (l & 15);
        const int slot = (ks * 4 + (l >> 4)) ^ (r & 7);
        av[mi] = *reinterpret_cast<const short8*>(As + r * 128 + slot * 8);
      }
#pragma unroll
      for (int nj = 0; nj < 4; ++nj) {
        const int r = wcol + nj * 16 + (l & 15);
        const int slot = (ks * 4 + (l >> 4)) ^ (r & 7);
        bv[nj] = *reinterpret_cast<const short8*>(Bs + r * 128 + slot * 8);
      }
#pragma unroll
      for (int mi = 0; mi < 2; ++mi)
#pragma unroll
        for (int nj = 0; nj < 4; ++nj)
          acc[mi][nj] = __builtin_amdgcn_mfma_f32_16x16x32_bf16(av[mi], bv[nj], acc[mi][nj], 0, 0, 0);
    }
    __syncthreads();
  }

  // Epilogue: stage 64x256 (bias+relu, stride 264) -> 64B/thread dense stores
#pragma unroll
  for (int nj = 0; nj < 4; ++nj) {
    const int col = wcol + nj * 16 + (l & 15);
    const float bvv = bias[col];
#pragma unroll
    for (int mi = 0; mi < 2; ++mi)
#pragma unroll
      for (int e = 0; e < 4; ++e) {
        const int row = wrow + mi * 16 + (l >> 4) * 4 + e;
        lds[row * 264 + col] = f2b(fmaxf(acc[mi][nj][e] + bvv, 0.f));
      }
  }
  __syncthreads();
  {
    const int r2 = t >> 3, s2 = t & 7;
    const unsigned short* src = lds + r2 * 264 + s2 * 32;
    const uint4 v0 = *reinterpret_cast<const uint4*>(src);
    const uint4 v1 = *reinterpret_cast<const uint4*>(src + 8);
    const uint4 v2 = *reinterpret_cast<const uint4*>(src + 16);
    const uint4 v3 = *reinterpret_cast<const uint4*>(src + 24);
    uint4* dst = reinterpret_cast<uint4*>(E + (size_t)(m0 + r2) * 256 + s2 * 32);
    dst[0] = v0; dst[1] = v1; dst[2] = v2; dst[3] = v3;
  }
}

// ---------------------------------------------------------------------------
// GX GEMM (R9 form): GX = vall @ Wx + b_gru (M=112000, N=768, K=256). 64x256.
// ---------------------------------------------------------------------------
__global__ __launch_bounds__(512) void gx_gemm(const unsigned short* __restrict__ Abf,
                                               const unsigned short* __restrict__ W2t,
                                               const float* __restrict__ bias,
                                               unsigned short* __restrict__ GX) {
  __shared__ __align__(16) unsigned short lds[20480];  // As 4096 | Bs 16384
  unsigned short* As = lds;
  unsigned short* Bs = lds + 4096;
  const int t = threadIdx.x, w = t >> 6, l = t & 63;
  const int work = xcd_swz(blockIdx.x, 656, 2);   // 5250 = 8*656+2
  const int m0 = (work / 3) * 64, n0 = (work % 3) * 256;
  const int srow = l >> 3, scol = ((l & 7) ^ srow) * 8;
  const int wrow = (w >> 2) * 32, wcol = (w & 3) * 64;

  f32x4 acc[2][4];
#pragma unroll
  for (int i = 0; i < 2; ++i)
#pragma unroll
    for (int j = 0; j < 4; ++j) acc[i][j] = {0.f, 0.f, 0.f, 0.f};

#pragma unroll
  for (int c = 0; c < 4; ++c) {
    gld16(Abf + (size_t)(m0 + 8 * w + srow) * 256 + c * 64 + scol, (void*)(As + w * 512));
#pragma unroll
    for (int i = 0; i < 4; ++i) {
      const int seg = 4 * w + i;
      gld16(W2t + (size_t)(n0 + 8 * seg + srow) * 512 + c * 64 + scol, (void*)(Bs + seg * 512));
    }
    __syncthreads();
#pragma unroll
    for (int ks = 0; ks < 2; ++ks) {
      short8 av[2], bv[4];
#pragma unroll
      for (int mi = 0; mi < 2; ++mi) {
        const int r = wrow + mi * 16 + (l & 15);
        const int slot = (ks * 4 + (l >> 4)) ^ (r & 7);
        av[mi] = *reinterpret_cast<const short8*>(As + r * 64 + slot * 8);
      }
#pragma unroll
      for (int nj = 0; nj < 4; ++nj) {
        const int r = wcol + nj * 16 + (l & 15);
        const int slot = (ks * 4 + (l >> 4)) ^ (r & 7);
        bv[nj] = *reinterpret_cast<const short8*>(Bs + r * 64 + slot * 8);
      }
#pragma unroll
      for (int mi = 0; mi < 2; ++mi)
#pragma unroll
        for (int nj = 0; nj < 4; ++nj)
          acc[mi][nj] = __builtin_amdgcn_mfma_f32_16x16x32_bf16(av[mi], bv[nj], acc[mi][nj], 0, 0, 0);
    }
    __syncthreads();
  }

#pragma unroll
  for (int nj = 0; nj < 4; ++nj) {
    const int col = wcol + nj * 16 + (l & 15);
    const float bvv = bias[n0 + col];
#pragma unroll
    for (int mi = 0; mi < 2; ++mi)
#pragma unroll
      for (int e = 0; e < 4; ++e) {
        const int row = wrow + mi * 16 + (l >> 4) * 4 + e;
        lds[row * 264 + col] = f2b(acc[mi][nj][e] + bvv);
      }
  }
  __syncthreads();
  {
    const int r2 = t >> 3, s2 = t & 7;
    const unsigned short* src = lds + r2 * 264 + s2 * 32;
    const uint4 v0 = *reinterpret_cast<const uint4*>(src);
    const uint4 v1 = *reinterpret_cast<const uint4*>(src + 8);
    const uint4 v2 = *reinterpret_cast<const uint4*>(src + 16);
    const uint4 v3 = *reinterpret_cast<const uint4*>(src + 24);
    uint4* dst = reinterpret_cast<uint4*>(GX + (size_t)(m0 + r2) * 768 + n0 + s2 * 32);
    dst[0] = v0; dst[1] = v1; dst[2] = v2; dst[3] = v3;
  }
}

// ---------------------------------------------------------------------------
// l_time from bf16 embeddings
// ---------------------------------------------------------------------------
__global__ __launch_bounds__(256) void ltime_kernel(const unsigned short* __restrict__ ep,
                                                    const unsigned short* __restrict__ ea,
                                                    const unsigned short* __restrict__ ev,
                                                    float* __restrict__ partials) {
  const unsigned PO = 3584000u, VO = 44800u;
  const unsigned TOT = 2u * PO + VO;
  const unsigned SL = 512000u, SLV = 6400u;
  const float wbig = 1.f / (3.f * 7.f * 16000.f);
  const float wsmall = 1.f / (3.f * 7.f * 200.f);
  float local = 0.f;
  for (unsigned i = blockIdx.x * 256u + threadIdx.x; i < TOT; i += gridDim.x * 256u) {
    const unsigned short* base; unsigned off, sl; float wgt;
    if (i < 2u * PO) { base = (i < PO) ? ep : ea; off = (i < PO) ? i : i - PO; sl = SL; wgt = wbig; }
    else             { base = ev; off = i - 2u * PO; sl = SLV; wgt = wsmall; }
    const uint4 u0 = *reinterpret_cast<const uint4*>(base + (size_t)off * 8);
    const uint4 u1 = *reinterpret_cast<const uint4*>(base + (size_t)(off + sl) * 8);
    float s = 0.f, d;
    d = b2f_lo(u1.x) - b2f_lo(u0.x); s += d * d;
    d = b2f_hi(u1.x) - b2f_hi(u0.x); s += d * d;
    d = b2f_lo(u1.y) - b2f_lo(u0.y); s += d * d;
    d = b2f_hi(u1.y) - b2f_hi(u0.y); s += d * d;
    d = b2f_lo(u1.z) - b2f_lo(u0.z); s += d * d;
    d = b2f_hi(u1.z) - b2f_hi(u0.z); s += d * d;
    d = b2f_lo(u1.w) - b2f_lo(u0.w); s += d * d;
    d = b2f_hi(u1.w) - b2f_hi(u0.w); s += d * d;
    local += wgt * s;
  }
  __shared__ float red[256];
  red[threadIdx.x] = local;
  __syncthreads();
  for (int s = 128; s > 0; s >>= 1) {
    if (threadIdx.x < s) red[threadIdx.x] += red[threadIdx.x + s];
    __syncthreads();
  }
  if (threadIdx.x == 0) partials[blockIdx.x] = red[0];
}

// ---------------------------------------------------------------------------
// v_all bf16: wave per n, lane handles 4 cols
// ---------------------------------------------------------------------------
__global__ __launch_bounds__(256) void vall_kernel(const unsigned short* __restrict__ ep,
                                                   const unsigned short* __restrict__ ea,
                                                   const unsigned short* __restrict__ ev,
                                                   const int* __restrict__ aidx,
                                                   const int* __restrict__ vidx,
                                                   const float* __restrict__ wm,
                                                   unsigned short* __restrict__ vall) {
  const int w = threadIdx.x >> 6, l = threadIdx.x & 63;
  const int n = blockIdx.x * 4 + w;
  float w0 = wm[0], w1 = wm[1], w2 = wm[2];
  const float mx = fmaxf(w0, fmaxf(w1, w2));
  const float e0 = expf(w0 - mx), e1 = expf(w1 - mx), e2 = expf(w2 - mx);
  const float inv = 1.f / (e0 + e1 + e2);
  w0 = e0 * inv; w1 = e1 * inv; w2 = e2 * inv;
  const int a0 = aidx[n * 4 + 0], a1 = aidx[n * 4 + 1];
  const int a2 = aidx[n * 4 + 2], a3 = aidx[n * 4 + 3];
  const int vn = vidx[n];
  const int cb = l * 4;
  for (int t = 0; t < 7; ++t) {
    const size_t tb = (size_t)t * NP * HH;
    const uint2 ua0 = *reinterpret_cast<const uint2*>(ea + tb + (size_t)a0 * HH + cb);
    const uint2 ua1 = *reinterpret_cast<const uint2*>(ea + tb + (size_t)a1 * HH + cb);
    const uint2 ua2 = *reinterpret_cast<const uint2*>(ea + tb + (size_t)a2 * HH + cb);
    const uint2 ua3 = *reinterpret_cast<const uint2*>(ea + tb + (size_t)a3 * HH + cb);
    const uint2 uv  = *reinterpret_cast<const uint2*>(ev + (size_t)t * NV * HH + (size_t)vn * HH + cb);
    const uint2 up  = *reinterpret_cast<const uint2*>(ep + tb + (size_t)n * HH + cb);
    float o[4];
    o[0] = w0 * 0.25f * (b2f_lo(ua0.x) + b2f_lo(ua1.x) + b2f_lo(ua2.x) + b2f_lo(ua3.x)) + w1 * b2f_lo(uv.x) + w2 * b2f_lo(up.x);
    o[1] = w0 * 0.25f * (b2f_hi(ua0.x) + b2f_hi(ua1.x) + b2f_hi(ua2.x) + b2f_hi(ua3.x)) + w1 * b2f_hi(uv.x) + w2 * b2f_hi(up.x);
    o[2] = w0 * 0.25f * (b2f_lo(ua0.y) + b2f_lo(ua1.y) + b2f_lo(ua2.y) + b2f_lo(ua3.y)) + w1 * b2f_lo(uv.y) + w2 * b2f_lo(up.y);
    o[3] = w0 * 0.25f * (b2f_hi(ua0.y) + b2f_hi(ua1.y) + b2f_hi(ua2.y) + b2f_hi(ua3.y)) + w1 * b2f_hi(uv.y) + w2 * b2f_hi(up.y);
    uint2 ov; ov.x = cvt2(o[0], o[1]); ov.y = cvt2(o[2], o[3]);
    *reinterpret_cast<uint2*>(vall + tb + (size_t)n * HH + cb) = ov;
  }
}

// ---------------------------------------------------------------------------
// GRU step 0 (h=0): H0 = (1 - sigmoid(gz)) * tanh(gn)
// ---------------------------------------------------------------------------
__global__ __launch_bounds__(256) void gru_h0(const unsigned short* __restrict__ GX,
                                              unsigned short* __restrict__ H0) {
  const int idx = blockIdx.x * 256 + threadIdx.x;
  const int hrow = idx >> 6, jq = idx & 63;
  const int g = (hrow >= 32000) ? 2 : (hrow >= 16000 ? 1 : 0);
  const int n = hrow - g * 16000;
  const size_t gxrow = (size_t)(4 + g) * 16000 + n;
  const unsigned short* gp = GX + gxrow * 768 + jq * 4;
  const uint2 uz = *reinterpret_cast<const uint2*>(gp + 256);
  const uint2 un = *reinterpret_cast<const uint2*>(gp + 512);
  float h[4];
  h[0] = (1.f - sigm(b2f_lo(uz.x))) * tanhfast(b2f_lo(un.x));
  h[1] = (1.f - sigm(b2f_hi(uz.x))) * tanhfast(b2f_hi(un.x));
  h[2] = (1.f - sigm(b2f_lo(uz.y))) * tanhfast(b2f_lo(un.y));
  h[3] = (1.f - sigm(b2f_hi(uz.y))) * tanhfast(b2f_hi(un.y));
  uint2 o; o.x = cvt2(h[0], h[1]); o.y = cvt2(h[2], h[3]);
  *reinterpret_cast<uint2*>(H0 + (size_t)hrow * 256 + jq * 4) = o;
}

// ---------------------------------------------------------------------------
// GRU recurrent step l (1..4): acc = Hsrc @ Wh (K=256, 3 gates); (R9 version)
// ---------------------------------------------------------------------------
__global__ __launch_bounds__(512, 2) void gru_hstep(const unsigned short* __restrict__ GX,
                                                    const unsigned short* __restrict__ W2t,
                                                    const unsigned short* __restrict__ Hsrc,
                                                    unsigned short* __restrict__ Hdst,
                                                    int lstep) {
  __shared__ __align__(16) unsigned short lds[32768];  // As 8192 | Bs 24576
  unsigned short* As = lds;
  unsigned short* Bs = lds + 8192;
  const int t = threadIdx.x, w = t >> 6, l = t & 63;
  const int work = xcd_swz(blockIdx.x, 93, 6);  // 750 = 8*93+6
  const int bx = work >> 1, jb = work & 1;
  const int m0 = bx * 128, j0 = jb * 128;
  const int g = bx / 125;
  const size_t gxRowBase = (size_t)(4 + g - lstep) * 16000 + (size_t)(m0 - g * 16000);
  const int srow = l >> 3;
  const int scol = ((l & 7) ^ srow) * 8;
  const int wr = w >> 2, wj = w & 3;
  f32x4 acc[3][4][2];
#pragma unroll
  for (int gate = 0; gate < 3; ++gate)
#pragma unroll
    for (int mi = 0; mi < 4; ++mi)
#pragma unroll
      for (int nj = 0; nj < 2; ++nj) acc[gate][mi][nj] = {0.f, 0.f, 0.f, 0.f};

#pragma unroll
  for (int c = 0; c < 4; ++c) {
#pragma unroll
    for (int i = 0; i < 2; ++i) {
      const int seg = w * 2 + i;
      gld16(Hsrc + (size_t)(m0 + 8 * seg + srow) * 256 + c * 64 + scol, (void*)(As + seg * 512));
    }
#pragma unroll
    for (int i = 0; i < 6; ++i) {
      const int seg = w * 6 + i;
      const int tilerow = 8 * seg + srow;
      const int gate = tilerow >> 7, jj = tilerow & 127;
      gld16(W2t + (size_t)(gate * 256 + j0 + jj) * 512 + 256 + c * 64 + scol,
            (void*)(Bs + seg * 512));
    }
    __syncthreads();
#pragma unroll
    for (int ks = 0; ks < 2; ++ks) {
      short8 av[4];
#pragma unroll
      for (int mi = 0; mi < 4; ++mi) {
        const int r = wr * 64 + mi * 16 + (l & 15);
        const int slot = (ks * 4 + (l >> 4)) ^ (r & 7);
        av[mi] = *reinterpret_cast<const short8*>(As + r * 64 + slot * 8);
      }
#pragma unroll
      for (int gate = 0; gate < 3; ++gate) {
        short8 bv0, bv1;
        {
          const int r0 = gate * 128 + wj * 32 + (l & 15);
          const int s0 = (ks * 4 + (l >> 4)) ^ (r0 & 7);
          bv0 = *reinterpret_cast<const short8*>(Bs + r0 * 64 + s0 * 8);
          const int r1 = r0 + 16;
          const int s1 = (ks * 4 + (l >> 4)) ^ (r1 & 7);
          bv1 = *reinterpret_cast<const short8*>(Bs + r1 * 64 + s1 * 8);
        }
#pragma unroll
        for (int mi = 0; mi < 4; ++mi) {
          acc[gate][mi][0] = __builtin_amdgcn_mfma_f32_16x16x32_bf16(av[mi], bv0, acc[gate][mi][0], 0, 0, 0);
          acc[gate][mi][1] = __builtin_amdgcn_mfma_f32_16x16x32_bf16(av[mi], bv1, acc[gate][mi][1], 0, 0, 0);
        }
      }
    }
    __syncthreads();
  }
  // epilogue: gates -> LDS -> coalesced stores (wave tile 64 rows x 32 cols)
  unsigned short* ep = lds + w * 2560;  // 64 x 40 shorts
#pragma unroll
  for (int nj = 0; nj < 2; ++nj) {
    const int jcol = j0 + wj * 32 + nj * 16 + (l & 15);
#pragma unroll
    for (int mi = 0; mi < 4; ++mi) {
#pragma unroll
      for (int e = 0; e < 4; ++e) {
        const int rib = wr * 64 + mi * 16 + (l >> 4) * 4 + e;
        const size_t hidx = (size_t)(m0 + rib) * 256 + jcol;
        const size_t gxoff = (gxRowBase + rib) * 768 + jcol;
        const float aR = acc[0][mi][nj][e] + b2f(GX[gxoff]);
        const float aZ = acc[1][mi][nj][e] + b2f(GX[gxoff + 256]);
        const float hn = acc[2][mi][nj][e];
        const float xn = b2f(GX[gxoff + 512]);
        const float rg = sigm(aR);
        const float zg = sigm(aZ);
        const float ng = tanhfast(xn + rg * hn);
        const float ho = b2f(Hsrc[hidx]);
        const int rl = mi * 16 + (l >> 4) * 4 + e;
        ep[rl * 40 + nj * 16 + (l & 15)] = f2b((1.f - zg) * ng + zg * ho);
      }
    }
  }
  __syncthreads();
  {
    const int grow = m0 + wr * 64 + l;
#pragma unroll
    for (int j = 0; j < 4; ++j) {
      const uint4 v = *reinterpret_cast<const uint4*>(ep + l * 40 + j * 8);
      *reinterpret_cast<uint4*>(Hdst + (size_t)grow * 256 + j0 + wj * 32 + j * 8) = v;
    }
  }
}

// ---------------------------------------------------------------------------
// Survival head + per-row loss: thread per row
// ---------------------------------------------------------------------------
__device__ inline float softplusf(float x) { return x > 20.f ? x : log1pf(expf(x)); }

__global__ __launch_bounds__(256) void head_kernel(const unsigned short* __restrict__ Hbuf,
                                                   const float* __restrict__ We, const float* __restrict__ be,
                                                   const float* __restrict__ Wm, const float* __restrict__ bmu,
                                                   const float* __restrict__ Ws, const float* __restrict__ bsg,
                                                   const float* __restrict__ yt,
                                                   float* __restrict__ partials) {
  __shared__ float sWe[256], sWm[256], sWs[256];
  const int t = threadIdx.x;
  sWe[t] = We[t]; sWm[t] = Wm[t]; sWs[t] = Ws[t];
  __syncthreads();
  const int row = blockIdx.x * 256 + t;
  float loss = 0.f;
  if (row < 48000) {
    const unsigned short* h = Hbuf + (size_t)row * HH;
    float pe = 0.f, pm = 0.f, ps = 0.f;
#pragma unroll 4
    for (int k0 = 0; k0 < 256; k0 += 8) {
      const uint4 u = *reinterpret_cast<const uint4*>(h + k0);
      const float hv[8] = {b2f_lo(u.x), b2f_hi(u.x), b2f_lo(u.y), b2f_hi(u.y),
                           b2f_lo(u.z), b2f_hi(u.z), b2f_lo(u.w), b2f_hi(u.w)};
#pragma unroll
      for (int q = 0; q < 8; ++q) {
        const int k = k0 + q;
        pe += hv[q] * sWe[k]; pm += hv[q] * sWm[k]; ps += hv[q] * sWs[k];
      }
    }
    const float eta = softplusf(pe + be[0]);
    const float mu  = pm + bmu[0];
    const float sg  = softplusf(ps + bsg[0]) + 0.001f;
    const float inv = 1.f / (sg * 1.41421356237309515f);
    float prev = 0.f;
#pragma unroll
    for (int hz = 1; hz <= 5; ++hz) {
      const float z  = (logf((float)hz) - mu) * inv;
      const float yc = eta * 0.5f * (1.f + erff(z));
      const float yh = yc - prev; prev = yc;
      const float d  = log1pf(yt[(size_t)row * 5 + (hz - 1)] + 1.0f) - log1pf(yh);
      loss += d * d;
    }
  }
  __shared__ float red[256];
  red[t] = loss;
  __syncthreads();
  for (int s = 128; s > 0; s >>= 1) {
    if (t < s) red[t] += red[t + s];
    __syncthreads();
  }
  if (t == 0) partials[blockIdx.x] = red[0];
}

__global__ __launch_bounds__(256) void final_kernel(const float* __restrict__ lt,
                                                    const float* __restrict__ lp,
                                                    float* __restrict__ out) {
  __shared__ float r1[256], r2[256];
  float s1 = 0.f, s2 = 0.f;
  for (int i = threadIdx.x; i < 1024; i += 256) s1 += lt[i];
  for (int i = threadIdx.x; i < 188; i += 256) s2 += lp[i];
  r1[threadIdx.x] = s1; r2[threadIdx.x] = s2;
  __syncthreads();
  for (int s = 128; s > 0; s >>= 1) {
    if (threadIdx.x < s) { r1[threadIdx.x] += r1[threadIdx.x + s]; r2[threadIdx.x] += r2[threadIdx.x + s]; }
    __syncthreads();
  }
  if (threadIdx.x == 0) out[0] = r2[0] / 240000.f + 0.5f * r1[0];
}

// ---------------------------------------------------------------------------
extern "C" void kernel_launch(void* const* d_in, const int* in_sizes, int n_in,
                              void* d_out, int out_size, void* d_ws, size_t ws_size,
                              hipStream_t stream) {
  (void)in_sizes; (void)n_in; (void)out_size; (void)ws_size;
  const float* x_paper  = (const float*)d_in[0];
  const float* x_author = (const float*)d_in[1];
  const float* x_venue  = (const float*)d_in[2];
  const int*   aidx     = (const int*)d_in[3];
  const int*   vidx     = (const int*)d_in[4];
  const float* y_true   = (const float*)d_in[5];
  const float* W_paper  = (const float*)d_in[6];
  const float* b_paper  = (const float*)d_in[7];
  const float* W_author = (const float*)d_in[8];
  const float* b_author = (const float*)d_in[9];
  const float* W_venue  = (const float*)d_in[10];
  const float* b_venue  = (const float*)d_in[11];
  const float* w_meta   = (const float*)d_in[12];
  const float* Wx       = (const float*)d_in[13];
  const float* Wh       = (const float*)d_in[14];
  const float* b_gru    = (const float*)d_in[15];
  const float* W_eta    = (const float*)d_in[16];
  const float* b_eta    = (const float*)d_in[17];
  const float* W_mu     = (const float*)d_in[18];
  const float* b_mu     = (const float*)d_in[19];
  const float* W_sigma  = (const float*)d_in[20];
  const float* b_sigma  = (const float*)d_in[21];

  unsigned short* p = (unsigned short*)d_ws;
  unsigned short* va16 = p;  p += (size_t)7 * NP * 256;      // 28,672,000
  unsigned short* Hb0  = p;  p += (size_t)48000 * 256;       // 12,288,000
  unsigned short* Hb1  = p;  p += (size_t)48000 * 256;       // 12,288,000
  unsigned short* W2t  = p;  p += (size_t)768 * 512;         //    393,216
  unsigned short* GX   = p;  p += (size_t)112000 * 768;      // 86,016,000
  float* ltp = (float*)p;
  float* lpp = ltp + 1024;
  // overlays (inside GX region):
  unsigned short* ep16 = GX;
  unsigned short* ea16 = ep16 + (size_t)8 * NP * 256;
  unsigned short* ev16 = ea16 + (size_t)8 * NP * 256;
  unsigned short* Wtp  = ev16 + (size_t)8 * NV * 256;
  unsigned short* Wta  = Wtp + 65536;
  unsigned short* Wtv  = Wta + 65536;

  // merged packs
  pack_all<<<1536, 256, 0, stream>>>(W_paper, W_author, W_venue, Wx, Wh,
                                     Wtp, Wta, Wtv, W2t);

  // merged embeddings (paper 2000 | author 2000 | venue 25), BK=128
  embed_all<<<4025, 512, 0, stream>>>(x_paper, x_author, x_venue, Wtp, Wta, Wtv,
                                      b_paper, b_author, b_venue, ep16, ea16, ev16);

  ltime_kernel<<<1024, 256, 0, stream>>>(ep16, ea16, ev16, ltp);
  vall_kernel<<<NP / 4, 256, 0, stream>>>(ep16, ea16, ev16, aidx, vidx, w_meta, va16);

  // GX = vall @ Wx + b_gru
  gx_gemm<<<5250, 512, 0, stream>>>(va16, W2t, b_gru, GX);

  // GRU: step0 elementwise, then 4 recurrent MFMA steps (ping-pong)
  gru_h0<<<12000, 256, 0, stream>>>(GX, Hb0);
  gru_hstep<<<750, 512, 0, stream>>>(GX, W2t, Hb0, Hb1, 1);
  gru_hstep<<<750, 512, 0, stream>>>(GX, W2t, Hb1, Hb0, 2);
  gru_hstep<<<750, 512, 0, stream>>>(GX, W2t, Hb0, Hb1, 3);
  gru_hstep<<<750, 512, 0, stream>>>(GX, W2t, Hb1, Hb0, 4);

  head_kernel<<<188, 256, 0, stream>>>(Hb0, W_eta, b_eta, W_mu, b_mu, W_sigma, b_sigma,
                                       y_true, lpp);
  final_kernel<<<1, 256, 0, stream>>>(ltp, lpp, (float*)d_out);
}

// Round 16
// 542.311 us; speedup vs baseline: 1.5930x; 1.0344x over previous
//
#include <hip/hip_runtime.h>
#include <cmath>

#define NP  16000
#define NV  200
#define HH  256

typedef short short8 __attribute__((ext_vector_type(8)));
typedef float f32x4  __attribute__((ext_vector_type(4)));

__device__ __forceinline__ unsigned short f2b(float f) {
  union { float f; unsigned u; } x; x.f = f;
  unsigned r = x.u + 0x7fffu + ((x.u >> 16) & 1u);
  return (unsigned short)(r >> 16);
}
__device__ __forceinline__ float b2f(unsigned short h) {
  union { unsigned u; float f; } x; x.u = ((unsigned)h) << 16;
  return x.f;
}
__device__ __forceinline__ float b2f_lo(unsigned u) {
  union { unsigned v; float f; } x; x.v = u << 16; return x.f;
}
__device__ __forceinline__ float b2f_hi(unsigned u) {
  union { unsigned v; float f; } x; x.v = u & 0xffff0000u; return x.f;
}
__device__ __forceinline__ unsigned cvt2(float a, float b) {
  unsigned r;
  asm("v_cvt_pk_bf16_f32 %0, %1, %2" : "=v"(r) : "v"(a), "v"(b));
  return r;
}
__device__ __forceinline__ void gld16(const void* g, void* l) {
  __builtin_amdgcn_global_load_lds((const __attribute__((address_space(1))) void*)g,
                                   (__attribute__((address_space(3))) void*)l, 16, 0, 0);
}
__device__ __forceinline__ float sigm(float x) { return 1.f / (1.f + __expf(-x)); }
__device__ __forceinline__ float tanhfast(float x) {
  const float e = __expf(-2.f * fabsf(x));
  const float t = (1.f - e) / (1.f + e);
  return x < 0.f ? -t : t;
}
__device__ __forceinline__ int xcd_swz(int orig, int q, int r) {
  const int xcd = orig & 7, loc = orig >> 3;
  return (xcd < r ? xcd * (q + 1) : r * (q + 1) + (xcd - r) * q) + loc;
}

// ---------------------------------------------------------------------------
// Merged weight packs: blocks 0-255 Wtp | 256-511 Wta | 512-767 Wtv | 768-1535 W2t
__global__ __launch_bounds__(256) void pack_all(const float* __restrict__ Wp,
                                                const float* __restrict__ Wa,
                                                const float* __restrict__ Wv,
                                                const float* __restrict__ Wx,
                                                const float* __restrict__ Wh,
                                                unsigned short* __restrict__ Wtp,
                                                unsigned short* __restrict__ Wta,
                                                unsigned short* __restrict__ Wtv,
                                                unsigned short* __restrict__ W2t) {
  const int b = blockIdx.x, k = threadIdx.x;
  if (b < 768) {
    const float* W = b < 256 ? Wp : (b < 512 ? Wa : Wv);
    unsigned short* Wt = b < 256 ? Wtp : (b < 512 ? Wta : Wtv);
    const int n = b & 255;
    Wt[n * 256 + k] = f2b(W[k * 256 + n]);
  } else {
    const int col = b - 768;
    for (int kk = k; kk < 512; kk += 256)
      W2t[(size_t)col * 512 + kk] =
          f2b(kk < 256 ? Wx[(size_t)kk * 768 + col] : Wh[(size_t)(kk - 256) * 768 + col]);
  }
}

// ---------------------------------------------------------------------------
// Embed GEMM (R9 form, BK=64, conflict-free): E = relu(X @ W + b).
// Tile 64x256, 512 thr / 8 waves (2x4).
// ---------------------------------------------------------------------------
__global__ __launch_bounds__(512) void embed_all(
    const float* __restrict__ Xp, const float* __restrict__ Xa, const float* __restrict__ Xv,
    const unsigned short* __restrict__ Wtp, const unsigned short* __restrict__ Wta,
    const unsigned short* __restrict__ Wtv,
    const float* __restrict__ bp, const float* __restrict__ ba, const float* __restrict__ bvn,
    unsigned short* __restrict__ Ep, unsigned short* __restrict__ Ea,
    unsigned short* __restrict__ Ev) {
  __shared__ __align__(16) unsigned short lds[20480];  // As 4096 | Bs 16384 (shorts)
  unsigned short* As = lds;          // 64 rows x 64 k
  unsigned short* Bs = lds + 4096;   // 256 n  x 64 k
  const int t = threadIdx.x, w = t >> 6, l = t & 63;
  const int bid = blockIdx.x;
  const float* Xf; const unsigned short* Wt; const float* bias; unsigned short* E;
  int m0;
  if (bid < 2000)      { Xf = Xp; Wt = Wtp; bias = bp;  E = Ep; m0 = bid * 64; }
  else if (bid < 4000) { Xf = Xa; Wt = Wta; bias = ba;  E = Ea; m0 = (bid - 2000) * 64; }
  else                 { Xf = Xv; Wt = Wtv; bias = bvn; E = Ev; m0 = (bid - 4000) * 64; }
  const int srow = l >> 3, scol = ((l & 7) ^ srow) * 8;
  const int wrow = (w >> 2) * 32, wcol = (w & 3) * 64;
  const int arow = t >> 3, aseg = t & 7;
  const float* aptr = Xf + (size_t)(m0 + arow) * 256 + aseg * 8;

  f32x4 acc[2][4];
#pragma unroll
  for (int i = 0; i < 2; ++i)
#pragma unroll
    for (int j = 0; j < 4; ++j) acc[i][j] = {0.f, 0.f, 0.f, 0.f};

  float4 a0 = *reinterpret_cast<const float4*>(aptr);
  float4 a1 = *reinterpret_cast<const float4*>(aptr + 4);

#pragma unroll
  for (int c = 0; c < 4; ++c) {
#pragma unroll
    for (int i = 0; i < 4; ++i) {
      const int seg = 4 * w + i;
      gld16(Wt + (size_t)(8 * seg + srow) * 256 + c * 64 + scol, (void*)(Bs + seg * 512));
    }
    {
      uint4 u;
      u.x = cvt2(a0.x, a0.y); u.y = cvt2(a0.z, a0.w);
      u.z = cvt2(a1.x, a1.y); u.w = cvt2(a1.z, a1.w);
      const int slot = aseg ^ (arow & 7);
      *reinterpret_cast<uint4*>(As + arow * 64 + slot * 8) = u;
    }
    if (c < 3) {
      const float* np = aptr + (c + 1) * 64;
      a0 = *reinterpret_cast<const float4*>(np);
      a1 = *reinterpret_cast<const float4*>(np + 4);
    }
    __syncthreads();
#pragma unroll
    for (int ks = 0; ks < 2; ++ks) {
      short8 av[2], bv[4];
#pragma unroll
      for (int mi = 0; mi < 2; ++mi) {
        const int r = wrow + mi * 16 + (l & 15);
        const int slot = (ks * 4 + (l >> 4)) ^ (r & 7);
        av[mi] = *reinterpret_cast<const short8*>(As + r * 64 + slot * 8);
      }
#pragma unroll
      for (int nj = 0; nj < 4; ++nj) {
        const int r = wcol + nj * 16 + (l & 15);
        const int slot = (ks * 4 + (l >> 4)) ^ (r & 7);
        bv[nj] = *reinterpret_cast<const short8*>(Bs + r * 64 + slot * 8);
      }
#pragma unroll
      for (int mi = 0; mi < 2; ++mi)
#pragma unroll
        for (int nj = 0; nj < 4; ++nj)
          acc[mi][nj] = __builtin_amdgcn_mfma_f32_16x16x32_bf16(av[mi], bv[nj], acc[mi][nj], 0, 0, 0);
    }
    __syncthreads();
  }

  // Epilogue: stage 64x256 (bias+relu, stride 264) -> 64B/thread dense stores
#pragma unroll
  for (int nj = 0; nj < 4; ++nj) {
    const int col = wcol + nj * 16 + (l & 15);
    const float bvv = bias[col];
#pragma unroll
    for (int mi = 0; mi < 2; ++mi)
#pragma unroll
      for (int e = 0; e < 4; ++e) {
        const int row = wrow + mi * 16 + (l >> 4) * 4 + e;
        lds[row * 264 + col] = f2b(fmaxf(acc[mi][nj][e] + bvv, 0.f));
      }
  }
  __syncthreads();
  {
    const int r2 = t >> 3, s2 = t & 7;
    const unsigned short* src = lds + r2 * 264 + s2 * 32;
    const uint4 v0 = *reinterpret_cast<const uint4*>(src);
    const uint4 v1 = *reinterpret_cast<const uint4*>(src + 8);
    const uint4 v2 = *reinterpret_cast<const uint4*>(src + 16);
    const uint4 v3 = *reinterpret_cast<const uint4*>(src + 24);
    uint4* dst = reinterpret_cast<uint4*>(E + (size_t)(m0 + r2) * 256 + s2 * 32);
    dst[0] = v0; dst[1] = v1; dst[2] = v2; dst[3] = v3;
  }
}

// ---------------------------------------------------------------------------
// Fused l_time + v_all. Grid 4000 x 256 thr (4 waves). Wave w owns
// paper row n=4b+w (vall mix + paper ltime via one t=0..7 sweep) and
// author row n (ltime sweep). Blocks <50 also cover venue rows.
// ---------------------------------------------------------------------------
__global__ __launch_bounds__(256) void ltvall_kernel(
    const unsigned short* __restrict__ ep, const unsigned short* __restrict__ ea,
    const unsigned short* __restrict__ ev,
    const int* __restrict__ aidx, const int* __restrict__ vidx,
    const float* __restrict__ wm,
    unsigned short* __restrict__ vall, float* __restrict__ partials) {
  const int w = threadIdx.x >> 6, l = threadIdx.x & 63;
  const int n = blockIdx.x * 4 + w;
  const int cb = l * 4;
  float w0 = wm[0], w1 = wm[1], w2 = wm[2];
  const float mx = fmaxf(w0, fmaxf(w1, w2));
  const float e0 = expf(w0 - mx), e1 = expf(w1 - mx), e2 = expf(w2 - mx);
  const float inv = 1.f / (e0 + e1 + e2);
  w0 = e0 * inv; w1 = e1 * inv; w2 = e2 * inv;
  const int a0 = aidx[n * 4 + 0], a1 = aidx[n * 4 + 1];
  const int a2 = aidx[n * 4 + 2], a3 = aidx[n * 4 + 3];
  const int vn = vidx[n];
  const float wbig = 1.f / (3.f * 7.f * 16000.f);
  const float wsmall = 1.f / (3.f * 7.f * 200.f);
  float lt = 0.f;

  // paper sweep: vall (t<7) + paper ltime (t>=1)
  uint2 prevp;
  for (int t = 0; t < 8; ++t) {
    const size_t tb = (size_t)t * NP * HH;
    const uint2 up = *reinterpret_cast<const uint2*>(ep + tb + (size_t)n * HH + cb);
    if (t >= 1) {
      float d;
      d = b2f_lo(up.x) - b2f_lo(prevp.x); lt += wbig * d * d;
      d = b2f_hi(up.x) - b2f_hi(prevp.x); lt += wbig * d * d;
      d = b2f_lo(up.y) - b2f_lo(prevp.y); lt += wbig * d * d;
      d = b2f_hi(up.y) - b2f_hi(prevp.y); lt += wbig * d * d;
    }
    if (t < 7) {
      const uint2 ua0 = *reinterpret_cast<const uint2*>(ea + tb + (size_t)a0 * HH + cb);
      const uint2 ua1 = *reinterpret_cast<const uint2*>(ea + tb + (size_t)a1 * HH + cb);
      const uint2 ua2 = *reinterpret_cast<const uint2*>(ea + tb + (size_t)a2 * HH + cb);
      const uint2 ua3 = *reinterpret_cast<const uint2*>(ea + tb + (size_t)a3 * HH + cb);
      const uint2 uv  = *reinterpret_cast<const uint2*>(ev + ((size_t)t * NV + vn) * HH + cb);
      float o[4];
      o[0] = w0 * 0.25f * (b2f_lo(ua0.x) + b2f_lo(ua1.x) + b2f_lo(ua2.x) + b2f_lo(ua3.x)) + w1 * b2f_lo(uv.x) + w2 * b2f_lo(up.x);
      o[1] = w0 * 0.25f * (b2f_hi(ua0.x) + b2f_hi(ua1.x) + b2f_hi(ua2.x) + b2f_hi(ua3.x)) + w1 * b2f_hi(uv.x) + w2 * b2f_hi(up.x);
      o[2] = w0 * 0.25f * (b2f_lo(ua0.y) + b2f_lo(ua1.y) + b2f_lo(ua2.y) + b2f_lo(ua3.y)) + w1 * b2f_lo(uv.y) + w2 * b2f_lo(up.y);
      o[3] = w0 * 0.25f * (b2f_hi(ua0.y) + b2f_hi(ua1.y) + b2f_hi(ua2.y) + b2f_hi(ua3.y)) + w1 * b2f_hi(uv.y) + w2 * b2f_hi(up.y);
      uint2 ov; ov.x = cvt2(o[0], o[1]); ov.y = cvt2(o[2], o[3]);
      *reinterpret_cast<uint2*>(vall + tb + (size_t)n * HH + cb) = ov;
    }
    prevp = up;
  }
  // author ltime sweep (own row n)
  {
    uint2 prva;
    for (int t = 0; t < 8; ++t) {
      const uint2 ua = *reinterpret_cast<const uint2*>(ea + ((size_t)t * NP + n) * HH + cb);
      if (t >= 1) {
        float d;
        d = b2f_lo(ua.x) - b2f_lo(prva.x); lt += wbig * d * d;
        d = b2f_hi(ua.x) - b2f_hi(prva.x); lt += wbig * d * d;
        d = b2f_lo(ua.y) - b2f_lo(prva.y); lt += wbig * d * d;
        d = b2f_hi(ua.y) - b2f_hi(prva.y); lt += wbig * d * d;
      }
      prva = ua;
    }
  }
  // venue ltime (blocks < 50, one row per wave)
  if (blockIdx.x < 50) {
    const int nv2 = blockIdx.x * 4 + w;
    uint2 prvv;
    for (int t = 0; t < 8; ++t) {
      const uint2 uvv = *reinterpret_cast<const uint2*>(ev + ((size_t)t * NV + nv2) * HH + cb);
      if (t >= 1) {
        float d;
        d = b2f_lo(uvv.x) - b2f_lo(prvv.x); lt += wsmall * d * d;
        d = b2f_hi(uvv.x) - b2f_hi(prvv.x); lt += wsmall * d * d;
        d = b2f_lo(uvv.y) - b2f_lo(prvv.y); lt += wsmall * d * d;
        d = b2f_hi(uvv.y) - b2f_hi(prvv.y); lt += wsmall * d * d;
      }
      prvv = uvv;
    }
  }
  __shared__ float red[256];
  red[threadIdx.x] = lt;
  __syncthreads();
  for (int s = 128; s > 0; s >>= 1) {
    if (threadIdx.x < s) red[threadIdx.x] += red[threadIdx.x + s];
    __syncthreads();
  }
  if (threadIdx.x == 0) partials[blockIdx.x] = red[0];
}

// ---------------------------------------------------------------------------
// GX GEMM (R9 form): GX = vall @ Wx + b_gru (M=112000, N=768, K=256). 64x256.
// ---------------------------------------------------------------------------
__global__ __launch_bounds__(512) void gx_gemm(const unsigned short* __restrict__ Abf,
                                               const unsigned short* __restrict__ W2t,
                                               const float* __restrict__ bias,
                                               unsigned short* __restrict__ GX) {
  __shared__ __align__(16) unsigned short lds[20480];  // As 4096 | Bs 16384
  unsigned short* As = lds;
  unsigned short* Bs = lds + 4096;
  const int t = threadIdx.x, w = t >> 6, l = t & 63;
  const int work = xcd_swz(blockIdx.x, 656, 2);   // 5250 = 8*656+2
  const int m0 = (work / 3) * 64, n0 = (work % 3) * 256;
  const int srow = l >> 3, scol = ((l & 7) ^ srow) * 8;
  const int wrow = (w >> 2) * 32, wcol = (w & 3) * 64;

  f32x4 acc[2][4];
#pragma unroll
  for (int i = 0; i < 2; ++i)
#pragma unroll
    for (int j = 0; j < 4; ++j) acc[i][j] = {0.f, 0.f, 0.f, 0.f};

#pragma unroll
  for (int c = 0; c < 4; ++c) {
    gld16(Abf + (size_t)(m0 + 8 * w + srow) * 256 + c * 64 + scol, (void*)(As + w * 512));
#pragma unroll
    for (int i = 0; i < 4; ++i) {
      const int seg = 4 * w + i;
      gld16(W2t + (size_t)(n0 + 8 * seg + srow) * 512 + c * 64 + scol, (void*)(Bs + seg * 512));
    }
    __syncthreads();
#pragma unroll
    for (int ks = 0; ks < 2; ++ks) {
      short8 av[2], bv[4];
#pragma unroll
      for (int mi = 0; mi < 2; ++mi) {
        const int r = wrow + mi * 16 + (l & 15);
        const int slot = (ks * 4 + (l >> 4)) ^ (r & 7);
        av[mi] = *reinterpret_cast<const short8*>(As + r * 64 + slot * 8);
      }
#pragma unroll
      for (int nj = 0; nj < 4; ++nj) {
        const int r = wcol + nj * 16 + (l & 15);
        const int slot = (ks * 4 + (l >> 4)) ^ (r & 7);
        bv[nj] = *reinterpret_cast<const short8*>(Bs + r * 64 + slot * 8);
      }
#pragma unroll
      for (int mi = 0; mi < 2; ++mi)
#pragma unroll
        for (int nj = 0; nj < 4; ++nj)
          acc[mi][nj] = __builtin_amdgcn_mfma_f32_16x16x32_bf16(av[mi], bv[nj], acc[mi][nj], 0, 0, 0);
    }
    __syncthreads();
  }

#pragma unroll
  for (int nj = 0; nj < 4; ++nj) {
    const int col = wcol + nj * 16 + (l & 15);
    const float bvv = bias[n0 + col];
#pragma unroll
    for (int mi = 0; mi < 2; ++mi)
#pragma unroll
      for (int e = 0; e < 4; ++e) {
        const int row = wrow + mi * 16 + (l >> 4) * 4 + e;
        lds[row * 264 + col] = f2b(acc[mi][nj][e] + bvv);
      }
  }
  __syncthreads();
  {
    const int r2 = t >> 3, s2 = t & 7;
    const unsigned short* src = lds + r2 * 264 + s2 * 32;
    const uint4 v0 = *reinterpret_cast<const uint4*>(src);
    const uint4 v1 = *reinterpret_cast<const uint4*>(src + 8);
    const uint4 v2 = *reinterpret_cast<const uint4*>(src + 16);
    const uint4 v3 = *reinterpret_cast<const uint4*>(src + 24);
    uint4* dst = reinterpret_cast<uint4*>(GX + (size_t)(m0 + r2) * 768 + n0 + s2 * 32);
    dst[0] = v0; dst[1] = v1; dst[2] = v2; dst[3] = v3;
  }
}

// ---------------------------------------------------------------------------
// GRU step 0 (h=0): H0 = (1 - sigmoid(gz)) * tanh(gn)
// ---------------------------------------------------------------------------
__global__ __launch_bounds__(256) void gru_h0(const unsigned short* __restrict__ GX,
                                              unsigned short* __restrict__ H0) {
  const int idx = blockIdx.x * 256 + threadIdx.x;
  const int hrow = idx >> 6, jq = idx & 63;
  const int g = (hrow >= 32000) ? 2 : (hrow >= 16000 ? 1 : 0);
  const int n = hrow - g * 16000;
  const size_t gxrow = (size_t)(4 + g) * 16000 + n;
  const unsigned short* gp = GX + gxrow * 768 + jq * 4;
  const uint2 uz = *reinterpret_cast<const uint2*>(gp + 256);
  const uint2 un = *reinterpret_cast<const uint2*>(gp + 512);
  float h[4];
  h[0] = (1.f - sigm(b2f_lo(uz.x))) * tanhfast(b2f_lo(un.x));
  h[1] = (1.f - sigm(b2f_hi(uz.x))) * tanhfast(b2f_hi(un.x));
  h[2] = (1.f - sigm(b2f_lo(uz.y))) * tanhfast(b2f_lo(un.y));
  h[3] = (1.f - sigm(b2f_hi(uz.y))) * tanhfast(b2f_hi(un.y));
  uint2 o; o.x = cvt2(h[0], h[1]); o.y = cvt2(h[2], h[3]);
  *reinterpret_cast<uint2*>(H0 + (size_t)hrow * 256 + jq * 4) = o;
}

// ---------------------------------------------------------------------------
// GRU recurrent step l (1..4): acc = Hsrc @ Wh (K=256, 3 gates); (R9 version)
// ---------------------------------------------------------------------------
__global__ __launch_bounds__(512, 2) void gru_hstep(const unsigned short* __restrict__ GX,
                                                    const unsigned short* __restrict__ W2t,
                                                    const unsigned short* __restrict__ Hsrc,
                                                    unsigned short* __restrict__ Hdst,
                                                    int lstep) {
  __shared__ __align__(16) unsigned short lds[32768];  // As 8192 | Bs 24576
  unsigned short* As = lds;
  unsigned short* Bs = lds + 8192;
  const int t = threadIdx.x, w = t >> 6, l = t & 63;
  const int work = xcd_swz(blockIdx.x, 93, 6);  // 750 = 8*93+6
  const int bx = work >> 1, jb = work & 1;
  const int m0 = bx * 128, j0 = jb * 128;
  const int g = bx / 125;
  const size_t gxRowBase = (size_t)(4 + g - lstep) * 16000 + (size_t)(m0 - g * 16000);
  const int srow = l >> 3;
  const int scol = ((l & 7) ^ srow) * 8;
  const int wr = w >> 2, wj = w & 3;
  f32x4 acc[3][4][2];
#pragma unroll
  for (int gate = 0; gate < 3; ++gate)
#pragma unroll
    for (int mi = 0; mi < 4; ++mi)
#pragma unroll
      for (int nj = 0; nj < 2; ++nj) acc[gate][mi][nj] = {0.f, 0.f, 0.f, 0.f};

#pragma unroll
  for (int c = 0; c < 4; ++c) {
#pragma unroll
    for (int i = 0; i < 2; ++i) {
      const int seg = w * 2 + i;
      gld16(Hsrc + (size_t)(m0 + 8 * seg + srow) * 256 + c * 64 + scol, (void*)(As + seg * 512));
    }
#pragma unroll
    for (int i = 0; i < 6; ++i) {
      const int seg = w * 6 + i;
      const int tilerow = 8 * seg + srow;
      const int gate = tilerow >> 7, jj = tilerow & 127;
      gld16(W2t + (size_t)(gate * 256 + j0 + jj) * 512 + 256 + c * 64 + scol,
            (void*)(Bs + seg * 512));
    }
    __syncthreads();
#pragma unroll
    for (int ks = 0; ks < 2; ++ks) {
      short8 av[4];
#pragma unroll
      for (int mi = 0; mi < 4; ++mi) {
        const int r = wr * 64 + mi * 16 + (l & 15);
        const int slot = (ks * 4 + (l >> 4)) ^ (r & 7);
        av[mi] = *reinterpret_cast<const short8*>(As + r * 64 + slot * 8);
      }
#pragma unroll
      for (int gate = 0; gate < 3; ++gate) {
        short8 bv0, bv1;
        {
          const int r0 = gate * 128 + wj * 32 + (l & 15);
          const int s0 = (ks * 4 + (l >> 4)) ^ (r0 & 7);
          bv0 = *reinterpret_cast<const short8*>(Bs + r0 * 64 + s0 * 8);
          const int r1 = r0 + 16;
          const int s1 = (ks * 4 + (l >> 4)) ^ (r1 & 7);
          bv1 = *reinterpret_cast<const short8*>(Bs + r1 * 64 + s1 * 8);
        }
#pragma unroll
        for (int mi = 0; mi < 4; ++mi) {
          acc[gate][mi][0] = __builtin_amdgcn_mfma_f32_16x16x32_bf16(av[mi], bv0, acc[gate][mi][0], 0, 0, 0);
          acc[gate][mi][1] = __builtin_amdgcn_mfma_f32_16x16x32_bf16(av[mi], bv1, acc[gate][mi][1], 0, 0, 0);
        }
      }
    }
    __syncthreads();
  }
  // epilogue: gates -> LDS -> coalesced stores (wave tile 64 rows x 32 cols)
  unsigned short* ep = lds + w * 2560;  // 64 x 40 shorts
#pragma unroll
  for (int nj = 0; nj < 2; ++nj) {
    const int jcol = j0 + wj * 32 + nj * 16 + (l & 15);
#pragma unroll
    for (int mi = 0; mi < 4; ++mi) {
#pragma unroll
      for (int e = 0; e < 4; ++e) {
        const int rib = wr * 64 + mi * 16 + (l >> 4) * 4 + e;
        const size_t hidx = (size_t)(m0 + rib) * 256 + jcol;
        const size_t gxoff = (gxRowBase + rib) * 768 + jcol;
        const float aR = acc[0][mi][nj][e] + b2f(GX[gxoff]);
        const float aZ = acc[1][mi][nj][e] + b2f(GX[gxoff + 256]);
        const float hn = acc[2][mi][nj][e];
        const float xn = b2f(GX[gxoff + 512]);
        const float rg = sigm(aR);
        const float zg = sigm(aZ);
        const float ng = tanhfast(xn + rg * hn);
        const float ho = b2f(Hsrc[hidx]);
        const int rl = mi * 16 + (l >> 4) * 4 + e;
        ep[rl * 40 + nj * 16 + (l & 15)] = f2b((1.f - zg) * ng + zg * ho);
      }
    }
  }
  __syncthreads();
  {
    const int grow = m0 + wr * 64 + l;
#pragma unroll
    for (int j = 0; j < 4; ++j) {
      const uint4 v = *reinterpret_cast<const uint4*>(ep + l * 40 + j * 8);
      *reinterpret_cast<uint4*>(Hdst + (size_t)grow * 256 + j0 + wj * 32 + j * 8) = v;
    }
  }
}

// ---------------------------------------------------------------------------
// Survival head + per-row loss: thread per row
// ---------------------------------------------------------------------------
__device__ inline float softplusf(float x) { return x > 20.f ? x : log1pf(expf(x)); }

__global__ __launch_bounds__(256) void head_kernel(const unsigned short* __restrict__ Hbuf,
                                                   const float* __restrict__ We, const float* __restrict__ be,
                                                   const float* __restrict__ Wm, const float* __restrict__ bmu,
                                                   const float* __restrict__ Ws, const float* __restrict__ bsg,
                                                   const float* __restrict__ yt,
                                                   float* __restrict__ partials) {
  __shared__ float sWe[256], sWm[256], sWs[256];
  const int t = threadIdx.x;
  sWe[t] = We[t]; sWm[t] = Wm[t]; sWs[t] = Ws[t];
  __syncthreads();
  const int row = blockIdx.x * 256 + t;
  float loss = 0.f;
  if (row < 48000) {
    const unsigned short* h = Hbuf + (size_t)row * HH;
    float pe = 0.f, pm = 0.f, ps = 0.f;
#pragma unroll 4
    for (int k0 = 0; k0 < 256; k0 += 8) {
      const uint4 u = *reinterpret_cast<const uint4*>(h + k0);
      const float hv[8] = {b2f_lo(u.x), b2f_hi(u.x), b2f_lo(u.y), b2f_hi(u.y),
                           b2f_lo(u.z), b2f_hi(u.z), b2f_lo(u.w), b2f_hi(u.w)};
#pragma unroll
      for (int q = 0; q < 8; ++q) {
        const int k = k0 + q;
        pe += hv[q] * sWe[k]; pm += hv[q] * sWm[k]; ps += hv[q] * sWs[k];
      }
    }
    const float eta = softplusf(pe + be[0]);
    const float mu  = pm + bmu[0];
    const float sg  = softplusf(ps + bsg[0]) + 0.001f;
    const float inv = 1.f / (sg * 1.41421356237309515f);
    float prev = 0.f;
#pragma unroll
    for (int hz = 1; hz <= 5; ++hz) {
      const float z  = (logf((float)hz) - mu) * inv;
      const float yc = eta * 0.5f * (1.f + erff(z));
      const float yh = yc - prev; prev = yc;
      const float d  = log1pf(yt[(size_t)row * 5 + (hz - 1)] + 1.0f) - log1pf(yh);
      loss += d * d;
    }
  }
  __shared__ float red[256];
  red[t] = loss;
  __syncthreads();
  for (int s = 128; s > 0; s >>= 1) {
    if (t < s) red[t] += red[t + s];
    __syncthreads();
  }
  if (t == 0) partials[blockIdx.x] = red[0];
}

__global__ __launch_bounds__(256) void final_kernel(const float* __restrict__ lt,
                                                    const float* __restrict__ lp,
                                                    float* __restrict__ out) {
  __shared__ float r1[256], r2[256];
  float s1 = 0.f, s2 = 0.f;
  for (int i = threadIdx.x; i < 4000; i += 256) s1 += lt[i];
  for (int i = threadIdx.x; i < 188; i += 256) s2 += lp[i];
  r1[threadIdx.x] = s1; r2[threadIdx.x] = s2;
  __syncthreads();
  for (int s = 128; s > 0; s >>= 1) {
    if (threadIdx.x < s) { r1[threadIdx.x] += r1[threadIdx.x + s]; r2[threadIdx.x] += r2[threadIdx.x + s]; }
    __syncthreads();
  }
  if (threadIdx.x == 0) out[0] = r2[0] / 240000.f + 0.5f * r1[0];
}

// ---------------------------------------------------------------------------
extern "C" void kernel_launch(void* const* d_in, const int* in_sizes, int n_in,
                              void* d_out, int out_size, void* d_ws, size_t ws_size,
                              hipStream_t stream) {
  (void)in_sizes; (void)n_in; (void)out_size; (void)ws_size;
  const float* x_paper  = (const float*)d_in[0];
  const float* x_author = (const float*)d_in[1];
  const float* x_venue  = (const float*)d_in[2];
  const int*   aidx     = (const int*)d_in[3];
  const int*   vidx     = (const int*)d_in[4];
  const float* y_true   = (const float*)d_in[5];
  const float* W_paper  = (const float*)d_in[6];
  const float* b_paper  = (const float*)d_in[7];
  const float* W_author = (const float*)d_in[8];
  const float* b_author = (const float*)d_in[9];
  const float* W_venue  = (const float*)d_in[10];
  const float* b_venue  = (const float*)d_in[11];
  const float* w_meta   = (const float*)d_in[12];
  const float* Wx       = (const float*)d_in[13];
  const float* Wh       = (const float*)d_in[14];
  const float* b_gru    = (const float*)d_in[15];
  const float* W_eta    = (const float*)d_in[16];
  const float* b_eta    = (const float*)d_in[17];
  const float* W_mu     = (const float*)d_in[18];
  const float* b_mu     = (const float*)d_in[19];
  const float* W_sigma  = (const float*)d_in[20];
  const float* b_sigma  = (const float*)d_in[21];

  unsigned short* p = (unsigned short*)d_ws;
  unsigned short* va16 = p;  p += (size_t)7 * NP * 256;      // 28,672,000
  unsigned short* Hb0  = p;  p += (size_t)48000 * 256;       // 12,288,000
  unsigned short* Hb1  = p;  p += (size_t)48000 * 256;       // 12,288,000
  unsigned short* W2t  = p;  p += (size_t)768 * 512;         //    393,216
  unsigned short* GX   = p;  p += (size_t)112000 * 768;      // 86,016,000
  float* ltp = (float*)p;
  float* lpp = ltp + 4096;
  // overlays (inside GX region):
  unsigned short* ep16 = GX;
  unsigned short* ea16 = ep16 + (size_t)8 * NP * 256;
  unsigned short* ev16 = ea16 + (size_t)8 * NP * 256;
  unsigned short* Wtp  = ev16 + (size_t)8 * NV * 256;
  unsigned short* Wta  = Wtp + 65536;
  unsigned short* Wtv  = Wta + 65536;

  // merged packs
  pack_all<<<1536, 256, 0, stream>>>(W_paper, W_author, W_venue, Wx, Wh,
                                     Wtp, Wta, Wtv, W2t);

  // merged embeddings (paper 2000 | author 2000 | venue 25), BK=64
  embed_all<<<4025, 512, 0, stream>>>(x_paper, x_author, x_venue, Wtp, Wta, Wtv,
                                      b_paper, b_author, b_venue, ep16, ea16, ev16);

  // fused ltime + vall
  ltvall_kernel<<<4000, 256, 0, stream>>>(ep16, ea16, ev16, aidx, vidx, w_meta,
                                          va16, ltp);

  // GX = vall @ Wx + b_gru
  gx_gemm<<<5250, 512, 0, stream>>>(va16, W2t, b_gru, GX);

  // GRU: step0 elementwise, then 4 recurrent MFMA steps (ping-pong)
  gru_h0<<<12000, 256, 0, stream>>>(GX, Hb0);
  gru_hstep<<<750, 512, 0, stream>>>(GX, W2t, Hb0, Hb1, 1);
  gru_hstep<<<750, 512, 0, stream>>>(GX, W2t, Hb1, Hb0, 2);
  gru_hstep<<<750, 512, 0, stream>>>(GX, W2t, Hb0, Hb1, 3);
  gru_hstep<<<750, 512, 0, stream>>>(GX, W2t, Hb1, Hb0, 4);

  head_kernel<<<188, 256, 0, stream>>>(Hb0, W_eta, b_eta, W_mu, b_mu, W_sigma, b_sigma,
                                       y_true, lpp);
  final_kernel<<<1, 256, 0, stream>>>(ltp, lpp, (float*)d_out);
}